// Round 3
// baseline (513.901 us; speedup 1.0000x reference)
//
#include <hip/hip_runtime.h>

typedef float f32x4 __attribute__((ext_vector_type(4)));
typedef short s16x8 __attribute__((ext_vector_type(8)));

#define NB_    32
#define NLC    2048
#define NLT    512
#define ND     256
#define NCHUNK 512
#define NITER  (NCHUNK / 32)

__device__ __forceinline__ unsigned short f2bf(float f) {
    union { float f; unsigned int u; } v; v.f = f;
    unsigned int r = v.u + 0x7FFFu + ((v.u >> 16) & 1u);   // RNE to bf16
    return (unsigned short)(r >> 16);
}
__device__ __forceinline__ float bf2f(unsigned short u) {
    union { unsigned int u; float f; } v; v.u = (unsigned int)u << 16;
    return v.f;
}

// Zero the g2t (pass-B, atomically accumulated) region of out: 32 x 512 x 256 f32.
__global__ __launch_bounds__(256) void zero_g2t(float* __restrict__ out) {
    const int g = blockIdx.x * 256 + threadIdx.x;          // 0..262143
    #pragma unroll
    for (int k = 0; k < 4; ++k) {
        const int i = g + k * 262144;                      // float4 index, 0..1048575
        const int bb = i >> 15;                            // 32768 float4 per batch region
        const int off = i & 32767;
        *(float4*)(out + ((size_t)bb * (NLC + NLT) + NLC) * ND + (size_t)off * 4) =
            make_float4(0.f, 0.f, 0.f, 0.f);
    }
}

// ---------------------------------------------------------------------------
// Fused kernel, uniform 512-row KV chunks. 1024 blocks (XCD-chunk swizzled,
// passes interleaved). Block = 4 waves, 128 Q rows (32/wave).
//   pass B (even logical): Q=tgt 128 rows, KV=ctx chunk nc, atomicAdd epilogue
//   pass A (odd  logical): Q=ctx 128 rows, KV=tgt full,    direct-store epilogue
// Double-buffered LDS pipeline, ONE barrier per iter:
//   barrier; LOAD(t+1)->regs; COMPUTE(buf[cur]); WRITE(regs->buf[cur^1])
// K row-norms computed during staging (shfl-reduce + Kpart in LDS); q-norms
// from the bf16 Q fragments. No separate norms kernel, d_ws unused.
// ---------------------------------------------------------------------------
__global__ __launch_bounds__(256, 2) void fused_dist_attn(
    const float* __restrict__ ctx, const float* __restrict__ tgt,
    float* __restrict__ out)
{
    __shared__ __align__(16) unsigned short Klds[2][32 * 256];    // [n][d] swizzled
    __shared__ __align__(16) unsigned short VTlds[2][256 * 32];   // [d][n] swizzled
    __shared__ __align__(16) unsigned short Wlds[4 * 32 * 32];    // per-wave [m][n]
    __shared__ __align__(16) float Kpart[2][4][32];               // per-wave k2 partials

    const int phys = blockIdx.x;
    const int L = (phys & 7) * 128 + (phys >> 3);   // XCD-chunked logical id (1024%8==0)
    const int isB = (L & 1) == 0;
    const int idx = L >> 1;                          // 0..511 within pass
    const int b = idx >> 4;
    const float *Q, *KV;
    size_t outbase;
    if (isB) {
        const int mb = (idx >> 2) & 3, nc = idx & 3;
        Q = tgt + ((size_t)b * NLT + mb * 128) * ND;
        KV = ctx + ((size_t)b * NLC + nc * NCHUNK) * ND;
        outbase = ((size_t)b * (NLC + NLT) + NLC + mb * 128) * ND;
    } else {
        const int mb = idx & 15;
        Q = ctx + ((size_t)b * NLC + mb * 128) * ND;
        KV = tgt + (size_t)b * NLT * ND;
        outbase = ((size_t)b * (NLC + NLT) + mb * 128) * ND;
    }

    const int tid = threadIdx.x, wave = tid >> 6, lane = tid & 63;
    const int lr = lane & 15, lq = lane >> 4;

    // ---- Q fragments (B operand of S^T) + q2 from the bf16 values
    s16x8 qf[2][8];
    float q2r[2];
    #pragma unroll
    for (int mf = 0; mf < 2; ++mf) {
        const float* qrow = Q + (size_t)(wave * 32 + mf * 16 + lr) * ND;
        float q2 = 0.0f;
        #pragma unroll
        for (int kk = 0; kk < 8; ++kk) {
            const float4 a = *(const float4*)(qrow + kk * 32 + lq * 8);
            const float4 c = *(const float4*)(qrow + kk * 32 + lq * 8 + 4);
            s16x8 f;
            f[0]=(short)f2bf(a.x); f[1]=(short)f2bf(a.y); f[2]=(short)f2bf(a.z); f[3]=(short)f2bf(a.w);
            f[4]=(short)f2bf(c.x); f[5]=(short)f2bf(c.y); f[6]=(short)f2bf(c.z); f[7]=(short)f2bf(c.w);
            qf[mf][kk] = f;
            #pragma unroll
            for (int e = 0; e < 8; ++e) {
                const float x = bf2f((unsigned short)f[e]);
                q2 += x * x;
            }
        }
        q2 += __shfl_xor(q2, 16);   // sum over lq (lane bits 4-5): full 256-elem row
        q2 += __shfl_xor(q2, 32);
        q2r[mf] = q2;
    }

    f32x4 acc[2][16];
    #pragma unroll
    for (int mf = 0; mf < 2; ++mf)
        #pragma unroll
        for (int dt = 0; dt < 16; ++dt)
            acc[mf][dt] = (f32x4)(0.0f);

    // ---- staging: thread owns rows r4..r4+3, cols d4..d4+3 and d4+128..+131
    const int r4 = (tid & 7) << 2;
    const int d4 = (tid >> 3) << 2;
    float4 ldr[2][4];

    auto LOADT = [&](int n0) {
        #pragma unroll
        for (int i = 0; i < 2; ++i)
            #pragma unroll
            for (int rr = 0; rr < 4; ++rr)
                ldr[i][rr] = *(const float4*)(KV + (size_t)(n0 + r4 + rr) * ND + d4 + i * 128);
    };

    auto WRITET = [&](int sel) {
        float ps[4] = {0.f, 0.f, 0.f, 0.f};
        #pragma unroll
        for (int i = 0; i < 2; ++i) {
            const int dbase = d4 + i * 128;
            unsigned short kb[4][4];
            #pragma unroll
            for (int rr = 0; rr < 4; ++rr) {
                const float4 v = ldr[i][rr];
                kb[rr][0]=f2bf(v.x); kb[rr][1]=f2bf(v.y); kb[rr][2]=f2bf(v.z); kb[rr][3]=f2bf(v.w);
                #pragma unroll
                for (int e = 0; e < 4; ++e) { const float x = bf2f(kb[rr][e]); ps[rr] += x * x; }
                const int r = r4 + rr;
                *(ushort4*)&Klds[sel][r * 256 + (dbase ^ ((r & 7) << 3))] =
                    make_ushort4(kb[rr][0], kb[rr][1], kb[rr][2], kb[rr][3]);
            }
            #pragma unroll
            for (int dd = 0; dd < 4; ++dd) {
                const int dr = dbase + dd;
                *(ushort4*)&VTlds[sel][dr * 32 + (r4 ^ ((dr & 3) << 3))] =
                    make_ushort4(kb[0][dd], kb[1][dd], kb[2][dd], kb[3][dd]);
            }
        }
        // reduce row partials over lanes differing in bits 3..5 (d-coverage of wave)
        #pragma unroll
        for (int rr = 0; rr < 4; ++rr) {
            ps[rr] += __shfl_xor(ps[rr], 8);
            ps[rr] += __shfl_xor(ps[rr], 16);
            ps[rr] += __shfl_xor(ps[rr], 32);
        }
        if (lane < 8)
            *(float4*)&Kpart[sel][wave][lane * 4] = make_float4(ps[0], ps[1], ps[2], ps[3]);
    };

    LOADT(0);
    WRITET(0);

    #pragma unroll 2
    for (int t = 0; t < NITER; ++t) {
        __syncthreads();          // buf[sel] writes visible; prev reads of buf[sel^1] done
        const int sel = t & 1;
        if (t + 1 < NITER) LOADT((t + 1) * 32);   // prefetch: hides HBM under compute

        // ---- k2 for C/D rows n = ns*16 + lq*4 + j (sum 4 wave-partials)
        f32x4 k2v[2];
        #pragma unroll
        for (int ns = 0; ns < 2; ++ns) {
            f32x4 s = *(const f32x4*)&Kpart[sel][0][ns * 16 + lq * 4];
            s += *(const f32x4*)&Kpart[sel][1][ns * 16 + lq * 4];
            s += *(const f32x4*)&Kpart[sel][2][ns * 16 + lq * 4];
            s += *(const f32x4*)&Kpart[sel][3][ns * 16 + lq * 4];
            k2v[ns] = s;
        }

        // ---- S^T = K(A) . Q(B)
        f32x4 sacc[2][2];   // [ns][mf]
        sacc[0][0] = (f32x4)(0.0f); sacc[0][1] = (f32x4)(0.0f);
        sacc[1][0] = (f32x4)(0.0f); sacc[1][1] = (f32x4)(0.0f);
        #pragma unroll
        for (int kk = 0; kk < 8; ++kk) {
            const int cs = (kk * 32 + lq * 8) ^ ((lr & 7) << 3);
            const s16x8 kf0 = *(const s16x8*)&Klds[sel][lr * 256 + cs];
            const s16x8 kf1 = *(const s16x8*)&Klds[sel][(16 + lr) * 256 + cs];
            sacc[0][0] = __builtin_amdgcn_mfma_f32_16x16x32_bf16(kf0, qf[0][kk], sacc[0][0], 0, 0, 0);
            sacc[0][1] = __builtin_amdgcn_mfma_f32_16x16x32_bf16(kf0, qf[1][kk], sacc[0][1], 0, 0, 0);
            sacc[1][0] = __builtin_amdgcn_mfma_f32_16x16x32_bf16(kf1, qf[0][kk], sacc[1][0], 0, 0, 0);
            sacc[1][1] = __builtin_amdgcn_mfma_f32_16x16x32_bf16(kf1, qf[1][kk], sacc[1][1], 0, 0, 0);
        }

        // ---- weights -> Wlds (per-wave, b64 writes; same-wave RAW via lgkmcnt)
        #pragma unroll
        for (int ns = 0; ns < 2; ++ns) {
            const f32x4 k2 = k2v[ns];
            #pragma unroll
            for (int mf = 0; mf < 2; ++mf) {
                unsigned short w4[4];
                #pragma unroll
                for (int j = 0; j < 4; ++j) {
                    float d2 = q2r[mf] + k2[j] - 2.0f * sacc[ns][mf][j];
                    d2 = d2 > 0.0f ? d2 : 0.0f;
                    const float w = __builtin_amdgcn_rcpf(1.0f + __builtin_amdgcn_sqrtf(d2));
                    w4[j] = f2bf(w);
                }
                const int row = mf * 16 + lr;
                const int col = (ns * 16 + lq * 4) ^ ((row & 3) << 3);
                *(ushort4*)&Wlds[wave * 1024 + row * 32 + col] =
                    make_ushort4(w4[0], w4[1], w4[2], w4[3]);
            }
        }

        // ---- O^T += V^T(A) . W(B)
        s16x8 wfr[2];
        #pragma unroll
        for (int mf = 0; mf < 2; ++mf)
            wfr[mf] = *(const s16x8*)&Wlds[wave * 1024 + (mf * 16 + lr) * 32 +
                                           ((lq * 8) ^ ((lr & 3) << 3))];
        #pragma unroll
        for (int dt = 0; dt < 16; ++dt) {
            const int vr = dt * 16 + lr;
            const s16x8 vf = *(const s16x8*)&VTlds[sel][vr * 32 + ((lq * 8) ^ ((lr & 3) << 3))];
            acc[0][dt] = __builtin_amdgcn_mfma_f32_16x16x32_bf16(vf, wfr[0], acc[0][dt], 0, 0, 0);
            acc[1][dt] = __builtin_amdgcn_mfma_f32_16x16x32_bf16(vf, wfr[1], acc[1][dt], 0, 0, 0);
        }

        if (t + 1 < NITER) WRITET(sel ^ 1);   // waits vmcnt on prefetched regs
    }

    // ---- epilogue: O^T C/D (row d = dt*16+lq*4+j, col m = mf*16+lr)
    if (isB) {
        #pragma unroll
        for (int mf = 0; mf < 2; ++mf) {
            float* rowp = out + outbase + (size_t)(wave * 32 + mf * 16 + lr) * ND;
            #pragma unroll
            for (int dt = 0; dt < 16; ++dt)
                #pragma unroll
                for (int j = 0; j < 4; ++j)
                    atomicAdd(rowp + dt * 16 + lq * 4 + j, acc[mf][dt][j]);
        }
    } else {
        #pragma unroll
        for (int mf = 0; mf < 2; ++mf) {
            const size_t rowbase = outbase + (size_t)(wave * 32 + mf * 16 + lr) * ND;
            #pragma unroll
            for (int dt = 0; dt < 16; ++dt) {
                const f32x4 v = acc[mf][dt];
                *(float4*)(out + rowbase + dt * 16 + lq * 4) = make_float4(v[0], v[1], v[2], v[3]);
            }
        }
    }
}

extern "C" void kernel_launch(void* const* d_in, const int* in_sizes, int n_in,
                              void* d_out, int out_size, void* d_ws, size_t ws_size,
                              hipStream_t stream) {
    const float* ctx = (const float*)d_in[0];   // [32, 2048, 256] fp32
    const float* tgt = (const float*)d_in[1];   // [32, 512, 256] fp32
    float* out = (float*)d_out;                 // [32, 2560, 256] fp32

    zero_g2t<<<1024, 256, 0, stream>>>(out);
    fused_dist_attn<<<1024, 256, 0, stream>>>(ctx, tgt, out);
}

// Round 4
// 429.312 us; speedup vs baseline: 1.1970x; 1.1970x over previous
//
#include <hip/hip_runtime.h>

typedef float f32x4 __attribute__((ext_vector_type(4)));
typedef short s16x8 __attribute__((ext_vector_type(8)));

#define NB_    32
#define NLC    2048
#define NLT    512
#define ND     256
#define NCHUNK 512
#define NITER  (NCHUNK / 32)

__device__ __forceinline__ unsigned short f2bf(float f) {
    union { float f; unsigned int u; } v; v.f = f;
    unsigned int r = v.u + 0x7FFFu + ((v.u >> 16) & 1u);   // RNE to bf16
    return (unsigned short)(r >> 16);
}

// ---------------------------------------------------------------------------
// Fallback-path zero kernel (atomic epilogue needs zeroed g2t region).
// ---------------------------------------------------------------------------
__global__ __launch_bounds__(256) void zero_g2t(float* __restrict__ out) {
    const int g = blockIdx.x * 256 + threadIdx.x;
    #pragma unroll
    for (int k = 0; k < 4; ++k) {
        const int i = g + k * 262144;                 // float4 idx over [32][512][64]
        const int bb = i >> 15;
        const int off = i & 32767;
        *(float4*)(out + ((size_t)bb * (NLC + NLT) + NLC) * ND + (size_t)off * 4) =
            make_float4(0.f, 0.f, 0.f, 0.f);
    }
}

// ---------------------------------------------------------------------------
// Reduce kernel: g2t[b][row][d] = sum_nc part[(b*16+mb*4+nc)][r][d]
// ---------------------------------------------------------------------------
__global__ __launch_bounds__(256) void reduce_g2t(const float* __restrict__ part,
                                                  float* __restrict__ out) {
    const int g = blockIdx.x * 256 + threadIdx.x;
    #pragma unroll
    for (int k = 0; k < 4; ++k) {
        const int i = g + k * 262144;                 // float4 idx over [32][512][64]
        const int b = i >> 15;
        const int rem = i & 32767;
        const int row = rem >> 6;                     // 0..511
        const int d4 = (rem & 63) * 4;
        const int mb = row >> 7, r = row & 127;
        const size_t base = ((size_t)(b * 16 + mb * 4) * 32768) + (size_t)r * 256 + d4;
        float4 s0 = *(const float4*)(part + base);
        float4 s1 = *(const float4*)(part + base + 32768);
        float4 s2 = *(const float4*)(part + base + 65536);
        float4 s3 = *(const float4*)(part + base + 98304);
        *(float4*)(out + ((size_t)b * (NLC + NLT) + NLC + row) * ND + d4) =
            make_float4(s0.x + s1.x + s2.x + s3.x, s0.y + s1.y + s2.y + s3.y,
                        s0.z + s1.z + s2.z + s3.z, s0.w + s1.w + s2.w + s3.w);
    }
}

// ---------------------------------------------------------------------------
// Fused kernel, 1024 uniform blocks (512 KV rows each), 4 waves, 128 Q rows.
// Extension-GEMM: A' = [K | k^2 | 1] (LDS), B' = [-2Q ; 1 ; q^2] (regs)
//   -> sacc = d^2 directly; w = rcp(1+sqrt(max(d2,0))).
// Double-buffered, one barrier/iter, prefetch-to-regs early, write-late.
// Pass B writes fp32 partials (part!=0) or atomicAdd fallback (part==0).
// ---------------------------------------------------------------------------
__global__ __launch_bounds__(256, 2) void fused_dist_attn(
    const float* __restrict__ ctx, const float* __restrict__ tgt,
    float* __restrict__ out, float* __restrict__ part)
{
    __shared__ __align__(16) unsigned short Klds[2][32 * 256];   // [n][d] plain K=V
    __shared__ __align__(16) unsigned short VTlds[2][256 * 32];  // [d][n] transposed
    __shared__ __align__(16) unsigned short Wlds[4 * 32 * 32];   // per-wave [m][n]
    __shared__ unsigned int KextLds[2][32];                      // packed {k2, 1.0} bf16

    const int phys = blockIdx.x;
    const int L = (phys & 7) * 128 + (phys >> 3);   // XCD-chunked (1024%8==0, bijective)
    const int isB = (L & 1) == 0;
    const int idx = L >> 1;                          // 0..511 within pass
    const int b = idx >> 4;
    const float *Q, *KV;
    size_t outbase;
    if (isB) {
        const int mb = (idx >> 2) & 3, nc = idx & 3;
        Q = tgt + ((size_t)b * NLT + mb * 128) * ND;
        KV = ctx + ((size_t)b * NLC + nc * NCHUNK) * ND;
        outbase = ((size_t)b * (NLC + NLT) + NLC + mb * 128) * ND;
    } else {
        const int mb = idx & 15;
        Q = ctx + ((size_t)b * NLC + mb * 128) * ND;
        KV = tgt + (size_t)b * NLT * ND;
        outbase = ((size_t)b * (NLC + NLT) + mb * 128) * ND;
    }

    const int tid = threadIdx.x, wave = tid >> 6, lane = tid & 63;
    const int lr = lane & 15, lq = lane >> 4;

    // ---- Q fragments: hold -2*Q bf16; q2 from unscaled values
    s16x8 qf[2][8];
    s16x8 qe[2];                 // extension B-frag: k-slot0 -> 1.0, slot1 -> q2
    #pragma unroll
    for (int mf = 0; mf < 2; ++mf) {
        const float* qrow = Q + (size_t)(wave * 32 + mf * 16 + lr) * ND;
        float q2 = 0.0f;
        #pragma unroll
        for (int kk = 0; kk < 8; ++kk) {
            const float4 a = *(const float4*)(qrow + kk * 32 + lq * 8);
            const float4 c = *(const float4*)(qrow + kk * 32 + lq * 8 + 4);
            q2 += a.x*a.x + a.y*a.y + a.z*a.z + a.w*a.w;
            q2 += c.x*c.x + c.y*c.y + c.z*c.z + c.w*c.w;
            s16x8 f;
            f[0]=(short)f2bf(-2.f*a.x); f[1]=(short)f2bf(-2.f*a.y);
            f[2]=(short)f2bf(-2.f*a.z); f[3]=(short)f2bf(-2.f*a.w);
            f[4]=(short)f2bf(-2.f*c.x); f[5]=(short)f2bf(-2.f*c.y);
            f[6]=(short)f2bf(-2.f*c.z); f[7]=(short)f2bf(-2.f*c.w);
            qf[mf][kk] = f;
        }
        q2 += __shfl_xor(q2, 16);
        q2 += __shfl_xor(q2, 32);
        union { unsigned int u[4]; s16x8 v; } qu;
        qu.u[0] = (lq == 0) ? (0x3F80u | ((unsigned int)f2bf(q2) << 16)) : 0u;
        qu.u[1] = 0u; qu.u[2] = 0u; qu.u[3] = 0u;
        qe[mf] = qu.v;
    }

    f32x4 acc[2][16];
    #pragma unroll
    for (int mf = 0; mf < 2; ++mf)
        #pragma unroll
        for (int dt = 0; dt < 16; ++dt)
            acc[mf][dt] = (f32x4)(0.0f);

    // ---- staging ownership: wave w owns rows 8w..8w+7; thread: 4 rows x 8 cols
    const int r4 = 8 * wave + 4 * (lane & 1);
    const int d8 = (lane >> 1) * 8;
    float4 ldr[4][2];

    auto LOADT = [&](int n0) {
        #pragma unroll
        for (int rr = 0; rr < 4; ++rr)
            #pragma unroll
            for (int h = 0; h < 2; ++h)
                ldr[rr][h] = *(const float4*)(KV + (size_t)(n0 + r4 + rr) * ND + d8 + 4 * h);
    };

    auto WRITET = [&](int sel) {
        float ps[4];
        unsigned short kb[4][8];
        #pragma unroll
        for (int rr = 0; rr < 4; ++rr) {
            const float4 a = ldr[rr][0], c = ldr[rr][1];
            ps[rr] = a.x*a.x + a.y*a.y + a.z*a.z + a.w*a.w
                   + c.x*c.x + c.y*c.y + c.z*c.z + c.w*c.w;
            kb[rr][0]=f2bf(a.x); kb[rr][1]=f2bf(a.y); kb[rr][2]=f2bf(a.z); kb[rr][3]=f2bf(a.w);
            kb[rr][4]=f2bf(c.x); kb[rr][5]=f2bf(c.y); kb[rr][6]=f2bf(c.z); kb[rr][7]=f2bf(c.w);
            const int r = r4 + rr;
            *(s16x8*)&Klds[sel][r * 256 + (d8 ^ ((r & 7) << 3))] = *(const s16x8*)kb[rr];
        }
        #pragma unroll
        for (int dd = 0; dd < 8; ++dd) {
            const int d = d8 + dd;
            *(ushort4*)&VTlds[sel][d * 32 + (r4 ^ (((d >> 3) & 3) << 3))] =
                make_ushort4(kb[0][dd], kb[1][dd], kb[2][dd], kb[3][dd]);
        }
        #pragma unroll
        for (int rr = 0; rr < 4; ++rr) {
            ps[rr] += __shfl_xor(ps[rr], 2);
            ps[rr] += __shfl_xor(ps[rr], 4);
            ps[rr] += __shfl_xor(ps[rr], 8);
            ps[rr] += __shfl_xor(ps[rr], 16);
            ps[rr] += __shfl_xor(ps[rr], 32);
        }
        if (lane < 2) {
            #pragma unroll
            for (int rr = 0; rr < 4; ++rr)
                KextLds[sel][8 * wave + 4 * lane + rr] =
                    (unsigned int)f2bf(ps[rr]) | 0x3F800000u;   // lo=k2, hi=1.0
        }
    };

    LOADT(0);
    WRITET(0);

    #pragma unroll 2
    for (int t = 0; t < NITER; ++t) {
        __syncthreads();          // buf[sel]+Kext visible; prior reads of buf[sel^1] done
        const int sel = t & 1;
        if (t + 1 < NITER) LOADT((t + 1) * 32);   // prefetch under compute

        // ---- extension A-frags (k-slot0=k2, slot1=1.0; lq>0 lanes zero)
        unsigned int p0 = 0u, p1 = 0u;
        if (lq == 0) { p0 = KextLds[sel][lr]; p1 = KextLds[sel][16 + lr]; }
        union { unsigned int u[4]; s16x8 v; } keu0, keu1;
        keu0.u[0] = p0; keu0.u[1] = 0; keu0.u[2] = 0; keu0.u[3] = 0;
        keu1.u[0] = p1; keu1.u[1] = 0; keu1.u[2] = 0; keu1.u[3] = 0;

        // ---- S^T = [K|k2|1] . [-2Q;1;q2]  ->  sacc = d^2
        f32x4 sacc[2][2];   // [ns][mf]
        sacc[0][0] = (f32x4)(0.0f); sacc[0][1] = (f32x4)(0.0f);
        sacc[1][0] = (f32x4)(0.0f); sacc[1][1] = (f32x4)(0.0f);
        __builtin_amdgcn_s_setprio(1);
        #pragma unroll
        for (int kk = 0; kk < 8; ++kk) {
            const int cs = (kk * 32 + lq * 8) ^ ((lr & 7) << 3);
            const s16x8 kf0 = *(const s16x8*)&Klds[sel][lr * 256 + cs];
            const s16x8 kf1 = *(const s16x8*)&Klds[sel][(16 + lr) * 256 + cs];
            sacc[0][0] = __builtin_amdgcn_mfma_f32_16x16x32_bf16(kf0, qf[0][kk], sacc[0][0], 0, 0, 0);
            sacc[0][1] = __builtin_amdgcn_mfma_f32_16x16x32_bf16(kf0, qf[1][kk], sacc[0][1], 0, 0, 0);
            sacc[1][0] = __builtin_amdgcn_mfma_f32_16x16x32_bf16(kf1, qf[0][kk], sacc[1][0], 0, 0, 0);
            sacc[1][1] = __builtin_amdgcn_mfma_f32_16x16x32_bf16(kf1, qf[1][kk], sacc[1][1], 0, 0, 0);
        }
        sacc[0][0] = __builtin_amdgcn_mfma_f32_16x16x32_bf16(keu0.v, qe[0], sacc[0][0], 0, 0, 0);
        sacc[0][1] = __builtin_amdgcn_mfma_f32_16x16x32_bf16(keu0.v, qe[1], sacc[0][1], 0, 0, 0);
        sacc[1][0] = __builtin_amdgcn_mfma_f32_16x16x32_bf16(keu1.v, qe[0], sacc[1][0], 0, 0, 0);
        sacc[1][1] = __builtin_amdgcn_mfma_f32_16x16x32_bf16(keu1.v, qe[1], sacc[1][1], 0, 0, 0);
        __builtin_amdgcn_s_setprio(0);

        // ---- weights -> Wlds (per-wave; same-wave RAW via lgkmcnt)
        #pragma unroll
        for (int ns = 0; ns < 2; ++ns) {
            #pragma unroll
            for (int mf = 0; mf < 2; ++mf) {
                unsigned short w4[4];
                #pragma unroll
                for (int j = 0; j < 4; ++j) {
                    float d2 = sacc[ns][mf][j];
                    d2 = d2 > 0.0f ? d2 : 0.0f;
                    w4[j] = f2bf(__builtin_amdgcn_rcpf(1.0f + __builtin_amdgcn_sqrtf(d2)));
                }
                const int row = mf * 16 + lr;
                const int col = (ns * 16 + lq * 4) ^ ((row & 3) << 3);
                *(ushort4*)&Wlds[wave * 1024 + row * 32 + col] =
                    make_ushort4(w4[0], w4[1], w4[2], w4[3]);
            }
        }

        // ---- O^T += V^T(A) . W(B)
        s16x8 wfr[2];
        #pragma unroll
        for (int mf = 0; mf < 2; ++mf)
            wfr[mf] = *(const s16x8*)&Wlds[wave * 1024 + (mf * 16 + lr) * 32 +
                                           ((lq * 8) ^ ((lr & 3) << 3))];
        __builtin_amdgcn_s_setprio(1);
        #pragma unroll
        for (int dt = 0; dt < 16; ++dt) {
            const int vr = dt * 16 + lr;
            const s16x8 vf = *(const s16x8*)&VTlds[sel][vr * 32 +
                                                        ((lq * 8) ^ (((vr >> 3) & 3) << 3))];
            acc[0][dt] = __builtin_amdgcn_mfma_f32_16x16x32_bf16(vf, wfr[0], acc[0][dt], 0, 0, 0);
            acc[1][dt] = __builtin_amdgcn_mfma_f32_16x16x32_bf16(vf, wfr[1], acc[1][dt], 0, 0, 0);
        }
        __builtin_amdgcn_s_setprio(0);

        if (t + 1 < NITER) WRITET(sel ^ 1);   // vmcnt-waits prefetched regs; fills other buf
    }

    // ---- epilogue: O^T C/D (row d = dt*16+lq*4+j, col m = mf*16+lr)
    if (isB) {
        if (part) {
            float* p = part + (size_t)idx * 32768;
            #pragma unroll
            for (int mf = 0; mf < 2; ++mf) {
                const size_t rowbase = (size_t)(wave * 32 + mf * 16 + lr) * ND;
                #pragma unroll
                for (int dt = 0; dt < 16; ++dt) {
                    const f32x4 v = acc[mf][dt];
                    *(float4*)(p + rowbase + dt * 16 + lq * 4) = make_float4(v[0], v[1], v[2], v[3]);
                }
            }
        } else {
            #pragma unroll
            for (int mf = 0; mf < 2; ++mf) {
                float* rowp = out + outbase + (size_t)(wave * 32 + mf * 16 + lr) * ND;
                #pragma unroll
                for (int dt = 0; dt < 16; ++dt)
                    #pragma unroll
                    for (int j = 0; j < 4; ++j)
                        atomicAdd(rowp + dt * 16 + lq * 4 + j, acc[mf][dt][j]);
            }
        }
    } else {
        #pragma unroll
        for (int mf = 0; mf < 2; ++mf) {
            const size_t rowbase = outbase + (size_t)(wave * 32 + mf * 16 + lr) * ND;
            #pragma unroll
            for (int dt = 0; dt < 16; ++dt) {
                const f32x4 v = acc[mf][dt];
                *(float4*)(out + rowbase + dt * 16 + lq * 4) = make_float4(v[0], v[1], v[2], v[3]);
            }
        }
    }
}

extern "C" void kernel_launch(void* const* d_in, const int* in_sizes, int n_in,
                              void* d_out, int out_size, void* d_ws, size_t ws_size,
                              hipStream_t stream) {
    const float* ctx = (const float*)d_in[0];   // [32, 2048, 256] fp32
    const float* tgt = (const float*)d_in[1];   // [32, 512, 256] fp32
    float* out = (float*)d_out;                 // [32, 2560, 256] fp32

    const size_t need = (size_t)512 * 128 * 256 * 4;   // 67.1 MB partials
    if (ws_size >= need) {
        float* part = (float*)d_ws;
        fused_dist_attn<<<1024, 256, 0, stream>>>(ctx, tgt, out, part);
        reduce_g2t<<<1024, 256, 0, stream>>>(part, out);
    } else {
        zero_g2t<<<1024, 256, 0, stream>>>(out);
        fused_dist_attn<<<1024, 256, 0, stream>>>(ctx, tgt, out, nullptr);
    }
}

// Round 5
// 376.944 us; speedup vs baseline: 1.3633x; 1.1389x over previous
//
#include <hip/hip_runtime.h>

typedef float f32x4 __attribute__((ext_vector_type(4)));
typedef short s16x8 __attribute__((ext_vector_type(8)));

#define NB_    32
#define NLC    2048
#define NLT    512
#define ND     256
#define NCHUNK 512
#define NITER  (NCHUNK / 32)

__device__ __forceinline__ unsigned short f2bf(float f) {
    union { float f; unsigned int u; } v; v.f = f;
    unsigned int r = v.u + 0x7FFFu + ((v.u >> 16) & 1u);   // RNE to bf16
    return (unsigned short)(r >> 16);
}

__device__ __forceinline__ s16x8 cvt8(float4 a, float4 c, float s) {
    s16x8 f;
    f[0]=(short)f2bf(s*a.x); f[1]=(short)f2bf(s*a.y); f[2]=(short)f2bf(s*a.z); f[3]=(short)f2bf(s*a.w);
    f[4]=(short)f2bf(s*c.x); f[5]=(short)f2bf(s*c.y); f[6]=(short)f2bf(s*c.z); f[7]=(short)f2bf(s*c.w);
    return f;
}

// ---------------------------------------------------------------------------
// Norms prepass (R2-proven): rows 0..65535 = ctx (b*2048+c), 65536.. = tgt.
// ---------------------------------------------------------------------------
__global__ __launch_bounds__(256) void norms_kernel(
    const float* __restrict__ ctx, const float* __restrict__ tgt,
    float* __restrict__ norms)
{
    const int wave = threadIdx.x >> 6;
    const int lane = threadIdx.x & 63;
    const int rid = blockIdx.x * 4 + wave;
    const float* row;
    if (rid < NB_ * NLC) row = ctx + (size_t)rid * ND;
    else                 row = tgt + (size_t)(rid - NB_ * NLC) * ND;
    const float4 v = *(const float4*)(row + lane * 4);
    float s = v.x * v.x + v.y * v.y + v.z * v.z + v.w * v.w;
    #pragma unroll
    for (int off = 32; off >= 1; off >>= 1) s += __shfl_xor(s, off);
    if (lane == 0) norms[rid] = s;
}

// ---------------------------------------------------------------------------
// K1: weights GEMM. Block 256thr/4 waves = 128c x 128t tile; wave = 32c x 128t.
// S = (-2*ctx) . tgt^T via global-direct MFMA frags (no LDS in k-loop).
// Epilogue: w = rcp(1+sqrt(max(c2+t2+S,0))) -> LDS relay -> W[c][t] and WT[t][c].
// ---------------------------------------------------------------------------
__global__ __launch_bounds__(256, 3) void k1_weights(
    const float* __restrict__ ctx, const float* __restrict__ tgt,
    const float* __restrict__ norms,
    unsigned short* __restrict__ Wg, unsigned short* __restrict__ WTg)
{
    __shared__ __align__(16) unsigned short relay[4][16 * 128];

    const int phys = blockIdx.x;
    const int L = (phys & 7) * 256 + (phys >> 3);   // grid 2048, bijective
    const int b = L >> 6;
    const int r = L & 63;
    const int cb = r >> 2, tb = r & 3;

    const int tid = threadIdx.x, wave = tid >> 6, lane = tid & 63;
    const int lr = lane & 15, lq = lane >> 4;
    const int cw = cb * 128 + wave * 32;

    const float* ctxb = ctx + ((size_t)b * NLC + cw) * ND;
    const float* tgtb = tgt + ((size_t)b * NLT + tb * 128) * ND;

    f32x4 acc[2][8];
    #pragma unroll
    for (int mf = 0; mf < 2; ++mf)
        #pragma unroll
        for (int nf = 0; nf < 8; ++nf) acc[mf][nf] = (f32x4)(0.0f);

    #pragma unroll
    for (int kk = 0; kk < 8; ++kk) {
        const int ko = kk * 32 + lq * 8;
        s16x8 af[2];
        #pragma unroll
        for (int mf = 0; mf < 2; ++mf) {
            const float* p = ctxb + (size_t)(mf * 16 + lr) * ND + ko;
            af[mf] = cvt8(*(const float4*)p, *(const float4*)(p + 4), -2.0f);
        }
        #pragma unroll
        for (int nf = 0; nf < 8; ++nf) {
            const float* p = tgtb + (size_t)(nf * 16 + lr) * ND + ko;
            const s16x8 bf = cvt8(*(const float4*)p, *(const float4*)(p + 4), 1.0f);
            acc[0][nf] = __builtin_amdgcn_mfma_f32_16x16x32_bf16(af[0], bf, acc[0][nf], 0, 0, 0);
            acc[1][nf] = __builtin_amdgcn_mfma_f32_16x16x32_bf16(af[1], bf, acc[1][nf], 0, 0, 0);
        }
    }

    // norms
    float c2[2][4], t2[8];
    #pragma unroll
    for (int mf = 0; mf < 2; ++mf)
        #pragma unroll
        for (int j = 0; j < 4; ++j)
            c2[mf][j] = norms[b * NLC + cw + mf * 16 + lq * 4 + j];
    #pragma unroll
    for (int nf = 0; nf < 8; ++nf)
        t2[nf] = norms[NB_ * NLC + b * NLT + tb * 128 + nf * 16 + lr];

    #pragma unroll
    for (int mf = 0; mf < 2; ++mf) {
        // weights into per-wave relay [16c][128t], swizzled
        #pragma unroll
        for (int nf = 0; nf < 8; ++nf) {
            #pragma unroll
            for (int j = 0; j < 4; ++j) {
                float d2 = c2[mf][j] + t2[nf] + acc[mf][nf][j];
                d2 = d2 > 0.0f ? d2 : 0.0f;
                const float w = __builtin_amdgcn_rcpf(1.0f + __builtin_amdgcn_sqrtf(d2));
                const int row = lq * 4 + j;
                relay[wave][row * 128 + ((nf * 16 + lr) ^ ((row & 7) << 3))] = f2bf(w);
            }
        }
        __syncthreads();
        // W rows: lane -> row lane>>2, col chunk (lane&3)*32
        {
            const int rrow = lane >> 2;
            const int cbs = (lane & 3) * 32;
            const size_t wrow = ((size_t)b * NLC + cw + mf * 16 + rrow) * NLT + tb * 128;
            #pragma unroll
            for (int e = 0; e < 4; ++e) {
                const int colb = cbs + e * 8;
                const s16x8 v = *(const s16x8*)&relay[wave][rrow * 128 + (colb ^ ((rrow & 7) << 3))];
                *(s16x8*)&Wg[wrow + colb] = v;
            }
        }
        // WT cols: lane handles t-cols 2*lane, 2*lane+1
        #pragma unroll
        for (int c = 0; c < 2; ++c) {
            const int tc = (lane << 1) | c;
            unsigned short colv[16];
            #pragma unroll
            for (int rr = 0; rr < 16; ++rr)
                colv[rr] = relay[wave][rr * 128 + (tc ^ ((rr & 7) << 3))];
            const size_t wtrow = ((size_t)b * NLT + tb * 128 + tc) * NLC + cw + mf * 16;
            *(s16x8*)&WTg[wtrow]     = *(const s16x8*)&colv[0];
            *(s16x8*)&WTg[wtrow + 8] = *(const s16x8*)&colv[8];
        }
        __syncthreads();
    }
}

// ---------------------------------------------------------------------------
// K23: O^T GEMM. Block 512thr/8 waves = [64d x 512cols], k-tiles of 32.
//   mode 2: g2c^T = tgt^T . W      (out rows c, direct store)
//   mode 3: g2t^T = ctx^T . WT     (k-chunked c, fp32 partials)
//   mode 4: g2t^T full-k direct    (no-partials tier)
// A = srcT staged in LDS (transpose, bf16, dbuf 8KB); B = W/WT rows global.
// C/D row = d => float4 stores along d.
// ---------------------------------------------------------------------------
__global__ __launch_bounds__(512, 4) void k23_gemm(
    const float* __restrict__ src_all, const unsigned short* __restrict__ Bmat_all,
    float* __restrict__ outp, float* __restrict__ part, int mode)
{
    __shared__ __align__(16) unsigned short srcT[2][64 * 32];

    const int nwg = gridDim.x;
    const int phys = blockIdx.x;
    const int L = (phys % 8) * (nwg >> 3) + (phys >> 3);

    int b, db, ob, niter, kbase, ldb;
    const float* src; const unsigned short* B; float* outB;
    if (mode == 2) {
        b = L >> 4; const int j = L & 15; db = j & 3; ob = j >> 2;
        src = src_all + (size_t)b * NLT * ND; kbase = 0; niter = 16;
        B = Bmat_all + (size_t)b * NLC * NLT + (size_t)ob * 512 * NLT; ldb = NLT;
        outB = outp + ((size_t)b * (NLC + NLT) + ob * 512) * ND;
    } else if (mode == 3) {
        b = L >> 4; const int j = L & 15; db = j & 3; ob = j >> 2;
        src = src_all + (size_t)b * NLC * ND; kbase = ob * 512; niter = 16;
        B = Bmat_all + (size_t)b * NLT * NLC; ldb = NLC;
        outB = part + ((size_t)ob * NB_ + b) * NLT * ND;
    } else {  // mode 4
        b = L >> 2; db = L & 3; ob = 0;
        src = src_all + (size_t)b * NLC * ND; kbase = 0; niter = 64;
        B = Bmat_all + (size_t)b * NLT * NLC; ldb = NLC;
        outB = outp + ((size_t)b * (NLC + NLT) + NLC) * ND;
    }
    const int dbase = db * 64;

    const int tid = threadIdx.x, wave = tid >> 6, lane = tid & 63;
    const int lr = lane & 15, lq = lane >> 4;
    const int dq = wave & 1, oq = wave >> 1;

    const int kr = tid >> 4;            // 0..31 (k row in tile)
    const int dd4 = (tid & 15) * 4;     // 0..60 (d col base)
    float4 ldv;

    auto LOADT = [&](int kt) {
        ldv = *(const float4*)(src + (size_t)(kbase + kt * 32 + kr) * ND + dbase + dd4);
    };
    auto WRITET = [&](int sel) {
        const float vv[4] = {ldv.x, ldv.y, ldv.z, ldv.w};
        #pragma unroll
        for (int e = 0; e < 4; ++e) {
            const int row = dd4 + e;
            srcT[sel][row * 32 + (kr ^ (((row >> 1) & 3) << 3))] = f2bf(vv[e]);
        }
    };

    f32x4 acc[2][8];
    #pragma unroll
    for (int mf = 0; mf < 2; ++mf)
        #pragma unroll
        for (int nf = 0; nf < 8; ++nf) acc[mf][nf] = (f32x4)(0.0f);

    LOADT(0); WRITET(0);

    for (int t = 0; t < niter; ++t) {
        __syncthreads();
        const int sel = t & 1;
        if (t + 1 < niter) LOADT(t + 1);

        s16x8 af[2];
        #pragma unroll
        for (int mf = 0; mf < 2; ++mf) {
            const int drow = dq * 32 + mf * 16 + lr;
            af[mf] = *(const s16x8*)&srcT[sel][drow * 32 + ((lq * 8) ^ (((drow >> 1) & 3) << 3))];
        }
        #pragma unroll
        for (int nf = 0; nf < 8; ++nf) {
            const int col = oq * 128 + nf * 16 + lr;
            const s16x8 bf = *(const s16x8*)&B[(size_t)col * ldb + kbase + t * 32 + lq * 8];
            acc[0][nf] = __builtin_amdgcn_mfma_f32_16x16x32_bf16(af[0], bf, acc[0][nf], 0, 0, 0);
            acc[1][nf] = __builtin_amdgcn_mfma_f32_16x16x32_bf16(af[1], bf, acc[1][nf], 0, 0, 0);
        }
        if (t + 1 < niter) WRITET(sel ^ 1);
    }

    #pragma unroll
    for (int nf = 0; nf < 8; ++nf) {
        const int col = oq * 128 + nf * 16 + lr;
        #pragma unroll
        for (int mf = 0; mf < 2; ++mf) {
            const f32x4 v = acc[mf][nf];
            *(float4*)&outB[(size_t)col * ND + dbase + dq * 32 + mf * 16 + lq * 4] =
                make_float4(v[0], v[1], v[2], v[3]);
        }
    }
}

// ---------------------------------------------------------------------------
// Reduce 4 k-chunk partials into g2t region of out.
// ---------------------------------------------------------------------------
__global__ __launch_bounds__(256) void reduce_part(const float* __restrict__ part,
                                                   float* __restrict__ out) {
    const int g = blockIdx.x * 256 + threadIdx.x;
    #pragma unroll
    for (int k = 0; k < 4; ++k) {
        const int i = g + k * 262144;           // float4 idx over [32][512][64]
        const int b = i >> 15;
        const int rem = i & 32767;
        const int t = rem >> 6;
        const int d4 = (rem & 63) * 4;
        const size_t base = ((size_t)b * NLT + t) * ND + d4;
        const float4 s0 = *(const float4*)(part + base);
        const float4 s1 = *(const float4*)(part + base + 4194304);
        const float4 s2 = *(const float4*)(part + base + 8388608);
        const float4 s3 = *(const float4*)(part + base + 12582912);
        *(float4*)(out + ((size_t)b * (NLC + NLT) + NLC + t) * ND + d4) =
            make_float4(s0.x + s1.x + s2.x + s3.x, s0.y + s1.y + s2.y + s3.y,
                        s0.z + s1.z + s2.z + s3.z, s0.w + s1.w + s2.w + s3.w);
    }
}

// ===========================================================================
// R4 fused fallback (proven-correct) for small workspaces.
// ===========================================================================
__global__ __launch_bounds__(256) void zero_g2t(float* __restrict__ out) {
    const int g = blockIdx.x * 256 + threadIdx.x;
    #pragma unroll
    for (int k = 0; k < 4; ++k) {
        const int i = g + k * 262144;
        const int bb = i >> 15;
        const int off = i & 32767;
        *(float4*)(out + ((size_t)bb * (NLC + NLT) + NLC) * ND + (size_t)off * 4) =
            make_float4(0.f, 0.f, 0.f, 0.f);
    }
}

__global__ __launch_bounds__(256) void reduce_g2t(const float* __restrict__ part,
                                                  float* __restrict__ out) {
    const int g = blockIdx.x * 256 + threadIdx.x;
    #pragma unroll
    for (int k = 0; k < 4; ++k) {
        const int i = g + k * 262144;
        const int b = i >> 15;
        const int rem = i & 32767;
        const int row = rem >> 6;
        const int d4 = (rem & 63) * 4;
        const int mb = row >> 7, r = row & 127;
        const size_t base = ((size_t)(b * 16 + mb * 4) * 32768) + (size_t)r * 256 + d4;
        float4 s0 = *(const float4*)(part + base);
        float4 s1 = *(const float4*)(part + base + 32768);
        float4 s2 = *(const float4*)(part + base + 65536);
        float4 s3 = *(const float4*)(part + base + 98304);
        *(float4*)(out + ((size_t)b * (NLC + NLT) + NLC + row) * ND + d4) =
            make_float4(s0.x + s1.x + s2.x + s3.x, s0.y + s1.y + s2.y + s3.y,
                        s0.z + s1.z + s2.z + s3.z, s0.w + s1.w + s2.w + s3.w);
    }
}

__global__ __launch_bounds__(256, 2) void fused_dist_attn(
    const float* __restrict__ ctx, const float* __restrict__ tgt,
    float* __restrict__ out, float* __restrict__ part)
{
    __shared__ __align__(16) unsigned short Klds[2][32 * 256];
    __shared__ __align__(16) unsigned short VTlds[2][256 * 32];
    __shared__ __align__(16) unsigned short Wlds[4 * 32 * 32];
    __shared__ unsigned int KextLds[2][32];

    const int phys = blockIdx.x;
    const int L = (phys & 7) * 128 + (phys >> 3);
    const int isB = (L & 1) == 0;
    const int idx = L >> 1;
    const int b = idx >> 4;
    const float *Q, *KV;
    size_t outbase;
    if (isB) {
        const int mb = (idx >> 2) & 3, nc = idx & 3;
        Q = tgt + ((size_t)b * NLT + mb * 128) * ND;
        KV = ctx + ((size_t)b * NLC + nc * NCHUNK) * ND;
        outbase = ((size_t)b * (NLC + NLT) + NLC + mb * 128) * ND;
    } else {
        const int mb = idx & 15;
        Q = ctx + ((size_t)b * NLC + mb * 128) * ND;
        KV = tgt + (size_t)b * NLT * ND;
        outbase = ((size_t)b * (NLC + NLT) + mb * 128) * ND;
    }

    const int tid = threadIdx.x, wave = tid >> 6, lane = tid & 63;
    const int lr = lane & 15, lq = lane >> 4;

    s16x8 qf[2][8];
    s16x8 qe[2];
    #pragma unroll
    for (int mf = 0; mf < 2; ++mf) {
        const float* qrow = Q + (size_t)(wave * 32 + mf * 16 + lr) * ND;
        float q2 = 0.0f;
        #pragma unroll
        for (int kk = 0; kk < 8; ++kk) {
            const float4 a = *(const float4*)(qrow + kk * 32 + lq * 8);
            const float4 c = *(const float4*)(qrow + kk * 32 + lq * 8 + 4);
            q2 += a.x*a.x + a.y*a.y + a.z*a.z + a.w*a.w;
            q2 += c.x*c.x + c.y*c.y + c.z*c.z + c.w*c.w;
            qf[mf][kk] = cvt8(a, c, -2.0f);
        }
        q2 += __shfl_xor(q2, 16);
        q2 += __shfl_xor(q2, 32);
        union { unsigned int u[4]; s16x8 v; } qu;
        qu.u[0] = (lq == 0) ? (0x3F80u | ((unsigned int)f2bf(q2) << 16)) : 0u;
        qu.u[1] = 0u; qu.u[2] = 0u; qu.u[3] = 0u;
        qe[mf] = qu.v;
    }

    f32x4 acc[2][16];
    #pragma unroll
    for (int mf = 0; mf < 2; ++mf)
        #pragma unroll
        for (int dt = 0; dt < 16; ++dt)
            acc[mf][dt] = (f32x4)(0.0f);

    const int r4 = 8 * wave + 4 * (lane & 1);
    const int d8 = (lane >> 1) * 8;
    float4 ldr[4][2];

    auto LOADT = [&](int n0) {
        #pragma unroll
        for (int rr = 0; rr < 4; ++rr)
            #pragma unroll
            for (int h = 0; h < 2; ++h)
                ldr[rr][h] = *(const float4*)(KV + (size_t)(n0 + r4 + rr) * ND + d8 + 4 * h);
    };

    auto WRITET = [&](int sel) {
        float ps[4];
        unsigned short kb[4][8];
        #pragma unroll
        for (int rr = 0; rr < 4; ++rr) {
            const float4 a = ldr[rr][0], c = ldr[rr][1];
            ps[rr] = a.x*a.x + a.y*a.y + a.z*a.z + a.w*a.w
                   + c.x*c.x + c.y*c.y + c.z*c.z + c.w*c.w;
            kb[rr][0]=f2bf(a.x); kb[rr][1]=f2bf(a.y); kb[rr][2]=f2bf(a.z); kb[rr][3]=f2bf(a.w);
            kb[rr][4]=f2bf(c.x); kb[rr][5]=f2bf(c.y); kb[rr][6]=f2bf(c.z); kb[rr][7]=f2bf(c.w);
            const int r = r4 + rr;
            *(s16x8*)&Klds[sel][r * 256 + (d8 ^ ((r & 7) << 3))] = *(const s16x8*)kb[rr];
        }
        #pragma unroll
        for (int dd = 0; dd < 8; ++dd) {
            const int d = d8 + dd;
            *(ushort4*)&VTlds[sel][d * 32 + (r4 ^ (((d >> 3) & 3) << 3))] =
                make_ushort4(kb[0][dd], kb[1][dd], kb[2][dd], kb[3][dd]);
        }
        #pragma unroll
        for (int rr = 0; rr < 4; ++rr) {
            ps[rr] += __shfl_xor(ps[rr], 2);
            ps[rr] += __shfl_xor(ps[rr], 4);
            ps[rr] += __shfl_xor(ps[rr], 8);
            ps[rr] += __shfl_xor(ps[rr], 16);
            ps[rr] += __shfl_xor(ps[rr], 32);
        }
        if (lane < 2) {
            #pragma unroll
            for (int rr = 0; rr < 4; ++rr)
                KextLds[sel][8 * wave + 4 * lane + rr] =
                    (unsigned int)f2bf(ps[rr]) | 0x3F800000u;
        }
    };

    LOADT(0);
    WRITET(0);

    #pragma unroll 2
    for (int t = 0; t < NITER; ++t) {
        __syncthreads();
        const int sel = t & 1;
        if (t + 1 < NITER) LOADT((t + 1) * 32);

        unsigned int p0 = 0u, p1 = 0u;
        if (lq == 0) { p0 = KextLds[sel][lr]; p1 = KextLds[sel][16 + lr]; }
        union { unsigned int u[4]; s16x8 v; } keu0, keu1;
        keu0.u[0] = p0; keu0.u[1] = 0; keu0.u[2] = 0; keu0.u[3] = 0;
        keu1.u[0] = p1; keu1.u[1] = 0; keu1.u[2] = 0; keu1.u[3] = 0;

        f32x4 sacc[2][2];
        sacc[0][0] = (f32x4)(0.0f); sacc[0][1] = (f32x4)(0.0f);
        sacc[1][0] = (f32x4)(0.0f); sacc[1][1] = (f32x4)(0.0f);
        __builtin_amdgcn_s_setprio(1);
        #pragma unroll
        for (int kk = 0; kk < 8; ++kk) {
            const int cs = (kk * 32 + lq * 8) ^ ((lr & 7) << 3);
            const s16x8 kf0 = *(const s16x8*)&Klds[sel][lr * 256 + cs];
            const s16x8 kf1 = *(const s16x8*)&Klds[sel][(16 + lr) * 256 + cs];
            sacc[0][0] = __builtin_amdgcn_mfma_f32_16x16x32_bf16(kf0, qf[0][kk], sacc[0][0], 0, 0, 0);
            sacc[0][1] = __builtin_amdgcn_mfma_f32_16x16x32_bf16(kf0, qf[1][kk], sacc[0][1], 0, 0, 0);
            sacc[1][0] = __builtin_amdgcn_mfma_f32_16x16x32_bf16(kf1, qf[0][kk], sacc[1][0], 0, 0, 0);
            sacc[1][1] = __builtin_amdgcn_mfma_f32_16x16x32_bf16(kf1, qf[1][kk], sacc[1][1], 0, 0, 0);
        }
        sacc[0][0] = __builtin_amdgcn_mfma_f32_16x16x32_bf16(keu0.v, qe[0], sacc[0][0], 0, 0, 0);
        sacc[0][1] = __builtin_amdgcn_mfma_f32_16x16x32_bf16(keu0.v, qe[1], sacc[0][1], 0, 0, 0);
        sacc[1][0] = __builtin_amdgcn_mfma_f32_16x16x32_bf16(keu1.v, qe[0], sacc[1][0], 0, 0, 0);
        sacc[1][1] = __builtin_amdgcn_mfma_f32_16x16x32_bf16(keu1.v, qe[1], sacc[1][1], 0, 0, 0);
        __builtin_amdgcn_s_setprio(0);

        #pragma unroll
        for (int ns = 0; ns < 2; ++ns) {
            #pragma unroll
            for (int mf = 0; mf < 2; ++mf) {
                unsigned short w4[4];
                #pragma unroll
                for (int j = 0; j < 4; ++j) {
                    float d2 = sacc[ns][mf][j];
                    d2 = d2 > 0.0f ? d2 : 0.0f;
                    w4[j] = f2bf(__builtin_amdgcn_rcpf(1.0f + __builtin_amdgcn_sqrtf(d2)));
                }
                const int row = mf * 16 + lr;
                const int col = (ns * 16 + lq * 4) ^ ((row & 3) << 3);
                *(ushort4*)&Wlds[wave * 1024 + row * 32 + col] =
                    make_ushort4(w4[0], w4[1], w4[2], w4[3]);
            }
        }

        s16x8 wfr[2];
        #pragma unroll
        for (int mf = 0; mf < 2; ++mf)
            wfr[mf] = *(const s16x8*)&Wlds[wave * 1024 + (mf * 16 + lr) * 32 +
                                           ((lq * 8) ^ ((lr & 3) << 3))];
        __builtin_amdgcn_s_setprio(1);
        #pragma unroll
        for (int dt = 0; dt < 16; ++dt) {
            const int vr = dt * 16 + lr;
            const s16x8 vf = *(const s16x8*)&VTlds[sel][vr * 32 +
                                                        ((lq * 8) ^ (((vr >> 3) & 3) << 3))];
            acc[0][dt] = __builtin_amdgcn_mfma_f32_16x16x32_bf16(vf, wfr[0], acc[0][dt], 0, 0, 0);
            acc[1][dt] = __builtin_amdgcn_mfma_f32_16x16x32_bf16(vf, wfr[1], acc[1][dt], 0, 0, 0);
        }
        __builtin_amdgcn_s_setprio(0);

        if (t + 1 < NITER) WRITET(sel ^ 1);
    }

    if (isB) {
        if (part) {
            float* p = part + (size_t)idx * 32768;
            #pragma unroll
            for (int mf = 0; mf < 2; ++mf) {
                const size_t rowbase = (size_t)(wave * 32 + mf * 16 + lr) * ND;
                #pragma unroll
                for (int dt = 0; dt < 16; ++dt) {
                    const f32x4 v = acc[mf][dt];
                    *(float4*)(p + rowbase + dt * 16 + lq * 4) = make_float4(v[0], v[1], v[2], v[3]);
                }
            }
        } else {
            #pragma unroll
            for (int mf = 0; mf < 2; ++mf) {
                float* rowp = out + outbase + (size_t)(wave * 32 + mf * 16 + lr) * ND;
                #pragma unroll
                for (int dt = 0; dt < 16; ++dt)
                    #pragma unroll
                    for (int j = 0; j < 4; ++j)
                        atomicAdd(rowp + dt * 16 + lq * 4 + j, acc[mf][dt][j]);
            }
        }
    } else {
        #pragma unroll
        for (int mf = 0; mf < 2; ++mf) {
            const size_t rowbase = outbase + (size_t)(wave * 32 + mf * 16 + lr) * ND;
            #pragma unroll
            for (int dt = 0; dt < 16; ++dt) {
                const f32x4 v = acc[mf][dt];
                *(float4*)(out + rowbase + dt * 16 + lq * 4) = make_float4(v[0], v[1], v[2], v[3]);
            }
        }
    }
}

extern "C" void kernel_launch(void* const* d_in, const int* in_sizes, int n_in,
                              void* d_out, int out_size, void* d_ws, size_t ws_size,
                              hipStream_t stream) {
    const float* ctx = (const float*)d_in[0];   // [32, 2048, 256] fp32
    const float* tgt = (const float*)d_in[1];   // [32, 512, 256] fp32
    float* out = (float*)d_out;                 // [32, 2560, 256] fp32

    const size_t NORMS_B = (size_t)81920 * 4;                   //    327,680
    const size_t W_B     = (size_t)NB_ * NLC * NLT * 2;         // 67,108,864
    const size_t W_OFF   = NORMS_B;
    const size_t WT_OFF  = W_OFF + W_B;
    const size_t PART_OFF = WT_OFF + W_B;                       // 134,545,408
    const size_t PART_B  = (size_t)4 * NB_ * NLT * ND * 4;      // 67,108,864
    const size_t NEED_FULL = PART_OFF + PART_B;                 // 201,654,272
    const size_t NEED_T2   = PART_OFF;

    char* ws = (char*)d_ws;
    if (ws_size >= NEED_T2) {
        float* norms = (float*)ws;
        unsigned short* Wg  = (unsigned short*)(ws + W_OFF);
        unsigned short* WTg = (unsigned short*)(ws + WT_OFF);

        norms_kernel<<<20480, 256, 0, stream>>>(ctx, tgt, norms);
        k1_weights<<<2048, 256, 0, stream>>>(ctx, tgt, norms, Wg, WTg);
        k23_gemm<<<512, 512, 0, stream>>>(tgt, Wg, out, nullptr, 2);
        if (ws_size >= NEED_FULL) {
            float* part = (float*)(ws + PART_OFF);
            k23_gemm<<<512, 512, 0, stream>>>(ctx, WTg, out, part, 3);
            reduce_part<<<1024, 256, 0, stream>>>(part, out);
        } else {
            k23_gemm<<<128, 512, 0, stream>>>(ctx, WTg, out, nullptr, 4);
        }
    } else {
        const size_t need = (size_t)512 * 128 * 256 * 4;
        if (ws_size >= need) {
            float* part = (float*)d_ws;
            fused_dist_attn<<<1024, 256, 0, stream>>>(ctx, tgt, out, part);
            reduce_g2t<<<1024, 256, 0, stream>>>(part, out);
        } else {
            zero_g2t<<<1024, 256, 0, stream>>>(out);
            fused_dist_attn<<<1024, 256, 0, stream>>>(ctx, tgt, out, nullptr);
        }
    }
}

// Round 6
// 248.574 us; speedup vs baseline: 2.0674x; 1.5164x over previous
//
#include <hip/hip_runtime.h>

typedef float f32x4 __attribute__((ext_vector_type(4)));
typedef short s16x8 __attribute__((ext_vector_type(8)));

#define NB_    32
#define NLC    2048
#define NLT    512
#define ND     256
#define NCHUNK 512
#define NITER  (NCHUNK / 32)

__device__ __forceinline__ unsigned short f2bf(float f) {
    union { float f; unsigned int u; } v; v.f = f;
    unsigned int r = v.u + 0x7FFFu + ((v.u >> 16) & 1u);   // RNE to bf16
    return (unsigned short)(r >> 16);
}

__device__ __forceinline__ s16x8 cvt8(float4 a, float4 c, float s) {
    s16x8 f;
    f[0]=(short)f2bf(s*a.x); f[1]=(short)f2bf(s*a.y); f[2]=(short)f2bf(s*a.z); f[3]=(short)f2bf(s*a.w);
    f[4]=(short)f2bf(s*c.x); f[5]=(short)f2bf(s*c.y); f[6]=(short)f2bf(s*c.z); f[7]=(short)f2bf(s*c.w);
    return f;
}

// async global->LDS, 16B per lane (dest = wave-uniform base + lane*16)
__device__ __forceinline__ void glds16(const void* g, void* l) {
    __builtin_amdgcn_global_load_lds(
        (const __attribute__((address_space(1))) unsigned int*)g,
        (__attribute__((address_space(3))) unsigned int*)l, 16, 0, 0);
}

// ---------------------------------------------------------------------------
// Prep: bf16 copies of ctx/tgt + row squared-norms. One wave per row.
// rows 0..65535 = ctx, 65536..81919 = tgt.
// ---------------------------------------------------------------------------
__global__ __launch_bounds__(256) void prep_kernel(
    const float* __restrict__ ctx, const float* __restrict__ tgt,
    float* __restrict__ norms,
    unsigned short* __restrict__ ctxb, unsigned short* __restrict__ tgtb)
{
    const int wave = threadIdx.x >> 6;
    const int lane = threadIdx.x & 63;
    const int rid = blockIdx.x * 4 + wave;
    const float* row;
    unsigned short* drow;
    if (rid < NB_ * NLC) { row = ctx + (size_t)rid * ND; drow = ctxb + (size_t)rid * ND; }
    else { row = tgt + (size_t)(rid - NB_ * NLC) * ND; drow = tgtb + (size_t)(rid - NB_ * NLC) * ND; }
    const float4 v = *(const float4*)(row + lane * 4);
    *(ushort4*)(drow + lane * 4) = make_ushort4(f2bf(v.x), f2bf(v.y), f2bf(v.z), f2bf(v.w));
    float s = v.x * v.x + v.y * v.y + v.z * v.z + v.w * v.w;
    #pragma unroll
    for (int off = 32; off >= 1; off >>= 1) s += __shfl_xor(s, off);
    if (lane == 0) norms[rid] = s;
}

// ---------------------------------------------------------------------------
// K1 (m97-structure): S = ctx.tgt^T per batch via LDS-staged bf16 GEMM.
// 128c x 128t tile, BK=64, dbuf, global_load_lds(16B) with source pre-swizzle
// (LDS linear; slot ^= row&7 applied on BOTH global src and ds_read — rule 21).
// Epilogue: w = rcp(1+sqrt(max(c2+t2-2S,0))) -> relay -> W[c][t], WT[t][c].
// ---------------------------------------------------------------------------
__global__ __launch_bounds__(256, 2) void k1_weights(
    const unsigned short* __restrict__ ctxb, const unsigned short* __restrict__ tgtb,
    const float* __restrict__ norms,
    unsigned short* __restrict__ Wg, unsigned short* __restrict__ WTg)
{
    __shared__ __align__(16) unsigned short Alds[2][128 * 64];   // [c][k] swz
    __shared__ __align__(16) unsigned short Blds[2][128 * 64];   // [t][k] swz
    __shared__ __align__(16) unsigned short relay[4][16 * 128];

    const int phys = blockIdx.x;
    const int L = (phys & 7) * 256 + (phys >> 3);   // grid 2048, bijective
    const int b = L >> 6;
    const int r = L & 63;
    const int cb = r >> 2, tb = r & 3;

    const int tid = threadIdx.x, wave = tid >> 6, lane = tid & 63;
    const int lr = lane & 15, lq = lane >> 4;
    const int cw = cb * 128 + wave * 32;

    const unsigned short* Actx = ctxb + ((size_t)b * NLC + cb * 128) * ND;
    const unsigned short* Btgt = tgtb + ((size_t)b * NLT + tb * 128) * ND;

    // stage K-step ks into buf: rows 128 x k[ks*64,+64), 4 A-loads + 4 B-loads/wave
    auto STAGE = [&](int buf, int ks) {
        #pragma unroll
        for (int i = 0; i < 4; ++i) {
            const int q = wave * 4 + i;                 // 8-row chunk id
            const int rloc = q * 8 + (lane >> 3);
            const int gcol = (lane & 7) ^ (rloc & 7);   // source pre-swizzle
            glds16(Actx + (size_t)rloc * ND + ks * 64 + gcol * 8,
                   &Alds[buf][q * 512]);
            glds16(Btgt + (size_t)rloc * ND + ks * 64 + gcol * 8,
                   &Blds[buf][q * 512]);
        }
    };

    f32x4 acc[2][8];
    #pragma unroll
    for (int mf = 0; mf < 2; ++mf)
        #pragma unroll
        for (int nf = 0; nf < 8; ++nf) acc[mf][nf] = (f32x4)(0.0f);

    STAGE(0, 0);
    int buf = 0;
    for (int ks = 0; ks < 4; ++ks) {
        __syncthreads();                 // drains vmcnt -> buf ready
        if (ks < 3) STAGE(buf ^ 1, ks + 1);
        #pragma unroll
        for (int kk = 0; kk < 2; ++kk) {
            s16x8 af[2];
            #pragma unroll
            for (int mf = 0; mf < 2; ++mf) {
                const int row = wave * 32 + mf * 16 + lr;
                af[mf] = *(const s16x8*)&Alds[buf][row * 64 + (((kk * 4 + lq) ^ (row & 7)) * 8)];
            }
            #pragma unroll
            for (int nf = 0; nf < 8; ++nf) {
                const int row = nf * 16 + lr;
                const s16x8 bf = *(const s16x8*)&Blds[buf][row * 64 + (((kk * 4 + lq) ^ (row & 7)) * 8)];
                acc[0][nf] = __builtin_amdgcn_mfma_f32_16x16x32_bf16(af[0], bf, acc[0][nf], 0, 0, 0);
                acc[1][nf] = __builtin_amdgcn_mfma_f32_16x16x32_bf16(af[1], bf, acc[1][nf], 0, 0, 0);
            }
        }
        buf ^= 1;
    }

    // norms
    float c2[2][4], t2[8];
    #pragma unroll
    for (int mf = 0; mf < 2; ++mf)
        #pragma unroll
        for (int j = 0; j < 4; ++j)
            c2[mf][j] = norms[b * NLC + cw + mf * 16 + lq * 4 + j];
    #pragma unroll
    for (int nf = 0; nf < 8; ++nf)
        t2[nf] = norms[NB_ * NLC + b * NLT + tb * 128 + nf * 16 + lr];

    __syncthreads();
    #pragma unroll
    for (int mf = 0; mf < 2; ++mf) {
        // weights into per-wave relay [16c][128t], swizzled
        #pragma unroll
        for (int nf = 0; nf < 8; ++nf) {
            #pragma unroll
            for (int j = 0; j < 4; ++j) {
                float d2 = c2[mf][j] + t2[nf] - 2.0f * acc[mf][nf][j];
                d2 = d2 > 0.0f ? d2 : 0.0f;
                const float w = __builtin_amdgcn_rcpf(1.0f + __builtin_amdgcn_sqrtf(d2));
                const int row = lq * 4 + j;
                relay[wave][row * 128 + ((nf * 16 + lr) ^ ((row & 7) << 3))] = f2bf(w);
            }
        }
        __syncthreads();
        // W rows: lane -> row lane>>2, col chunk (lane&3)*32
        {
            const int rrow = lane >> 2;
            const int cbs = (lane & 3) * 32;
            const size_t wrow = ((size_t)b * NLC + cw + mf * 16 + rrow) * NLT + tb * 128;
            #pragma unroll
            for (int e = 0; e < 4; ++e) {
                const int colb = cbs + e * 8;
                const s16x8 v = *(const s16x8*)&relay[wave][rrow * 128 + (colb ^ ((rrow & 7) << 3))];
                *(s16x8*)&Wg[wrow + colb] = v;
            }
        }
        // WT cols: lane handles t-cols 2*lane, 2*lane+1
        #pragma unroll
        for (int c = 0; c < 2; ++c) {
            const int tc = (lane << 1) | c;
            unsigned short colv[16];
            #pragma unroll
            for (int rr = 0; rr < 16; ++rr)
                colv[rr] = relay[wave][rr * 128 + (tc ^ ((rr & 7) << 3))];
            const size_t wtrow = ((size_t)b * NLT + tb * 128 + tc) * NLC + cw + mf * 16;
            *(s16x8*)&WTg[wtrow]     = *(const s16x8*)&colv[0];
            *(s16x8*)&WTg[wtrow + 8] = *(const s16x8*)&colv[8];
        }
        __syncthreads();
    }
}

// ---------------------------------------------------------------------------
// K23: O^T GEMM (bf16 src). Block 512thr/8 waves = [64d x 512cols], k-tiles 32.
//   mode 2: g2c^T = tgt^T . W      mode 3: g2t^T k-chunked (partials)
//   mode 4: g2t^T full-k direct
// ---------------------------------------------------------------------------
__global__ __launch_bounds__(512, 4) void k23_gemm(
    const unsigned short* __restrict__ src_all, const unsigned short* __restrict__ Bmat_all,
    float* __restrict__ outp, float* __restrict__ part, int mode)
{
    __shared__ __align__(16) unsigned short srcT[2][64 * 32];

    const int nwg = gridDim.x;
    const int phys = blockIdx.x;
    const int L = (phys % 8) * (nwg >> 3) + (phys >> 3);

    int b, db, ob, niter, kbase, ldb;
    const unsigned short* src; const unsigned short* B; float* outB;
    if (mode == 2) {
        b = L >> 4; const int j = L & 15; db = j & 3; ob = j >> 2;
        src = src_all + (size_t)b * NLT * ND; kbase = 0; niter = 16;
        B = Bmat_all + (size_t)b * NLC * NLT + (size_t)ob * 512 * NLT; ldb = NLT;
        outB = outp + ((size_t)b * (NLC + NLT) + ob * 512) * ND;
    } else if (mode == 3) {
        b = L >> 4; const int j = L & 15; db = j & 3; ob = j >> 2;
        src = src_all + (size_t)b * NLC * ND; kbase = ob * 512; niter = 16;
        B = Bmat_all + (size_t)b * NLT * NLC; ldb = NLC;
        outB = part + ((size_t)ob * NB_ + b) * NLT * ND;
    } else {  // mode 4
        b = L >> 2; db = L & 3; ob = 0;
        src = src_all + (size_t)b * NLC * ND; kbase = 0; niter = 64;
        B = Bmat_all + (size_t)b * NLT * NLC; ldb = NLC;
        outB = outp + ((size_t)b * (NLC + NLT) + NLC) * ND;
    }
    const int dbase = db * 64;

    const int tid = threadIdx.x, wave = tid >> 6, lane = tid & 63;
    const int lr = lane & 15, lq = lane >> 4;
    const int dq = wave & 1, oq = wave >> 1;

    const int kr = tid >> 4;            // 0..31 (k row in tile)
    const int dd4 = (tid & 15) * 4;     // 0..60 (d col base)
    ushort4 ldv;

    auto LOADT = [&](int kt) {
        ldv = *(const ushort4*)(src + (size_t)(kbase + kt * 32 + kr) * ND + dbase + dd4);
    };
    auto WRITET = [&](int sel) {
        const unsigned short vv[4] = {ldv.x, ldv.y, ldv.z, ldv.w};
        #pragma unroll
        for (int e = 0; e < 4; ++e) {
            const int row = dd4 + e;
            srcT[sel][row * 32 + (kr ^ (((row >> 1) & 3) << 3))] = vv[e];
        }
    };

    f32x4 acc[2][8];
    #pragma unroll
    for (int mf = 0; mf < 2; ++mf)
        #pragma unroll
        for (int nf = 0; nf < 8; ++nf) acc[mf][nf] = (f32x4)(0.0f);

    LOADT(0); WRITET(0);

    for (int t = 0; t < niter; ++t) {
        __syncthreads();
        const int sel = t & 1;
        if (t + 1 < niter) LOADT(t + 1);

        s16x8 af[2];
        #pragma unroll
        for (int mf = 0; mf < 2; ++mf) {
            const int drow = dq * 32 + mf * 16 + lr;
            af[mf] = *(const s16x8*)&srcT[sel][drow * 32 + ((lq * 8) ^ (((drow >> 1) & 3) << 3))];
        }
        #pragma unroll
        for (int nf = 0; nf < 8; ++nf) {
            const int col = oq * 128 + nf * 16 + lr;
            const s16x8 bf = *(const s16x8*)&B[(size_t)col * ldb + kbase + t * 32 + lq * 8];
            acc[0][nf] = __builtin_amdgcn_mfma_f32_16x16x32_bf16(af[0], bf, acc[0][nf], 0, 0, 0);
            acc[1][nf] = __builtin_amdgcn_mfma_f32_16x16x32_bf16(af[1], bf, acc[1][nf], 0, 0, 0);
        }
        if (t + 1 < niter) WRITET(sel ^ 1);
    }

    #pragma unroll
    for (int nf = 0; nf < 8; ++nf) {
        const int col = oq * 128 + nf * 16 + lr;
        #pragma unroll
        for (int mf = 0; mf < 2; ++mf) {
            const f32x4 v = acc[mf][nf];
            *(float4*)&outB[(size_t)col * ND + dbase + dq * 32 + mf * 16 + lq * 4] =
                make_float4(v[0], v[1], v[2], v[3]);
        }
    }
}

// ---------------------------------------------------------------------------
// Reduce 4 k-chunk partials into g2t region of out.
// ---------------------------------------------------------------------------
__global__ __launch_bounds__(256) void reduce_part(const float* __restrict__ part,
                                                   float* __restrict__ out) {
    const int g = blockIdx.x * 256 + threadIdx.x;
    #pragma unroll
    for (int k = 0; k < 4; ++k) {
        const int i = g + k * 262144;           // float4 idx over [32][512][64]
        const int b = i >> 15;
        const int rem = i & 32767;
        const int t = rem >> 6;
        const int d4 = (rem & 63) * 4;
        const size_t base = ((size_t)b * NLT + t) * ND + d4;
        const float4 s0 = *(const float4*)(part + base);
        const float4 s1 = *(const float4*)(part + base + 4194304);
        const float4 s2 = *(const float4*)(part + base + 8388608);
        const float4 s3 = *(const float4*)(part + base + 12582912);
        *(float4*)(out + ((size_t)b * (NLC + NLT) + NLC + t) * ND + d4) =
            make_float4(s0.x + s1.x + s2.x + s3.x, s0.y + s1.y + s2.y + s3.y,
                        s0.z + s1.z + s2.z + s3.z, s0.w + s1.w + s2.w + s3.w);
    }
}

// ===========================================================================
// R4 fused fallback (proven-correct) for small workspaces.
// ===========================================================================
__global__ __launch_bounds__(256) void zero_g2t(float* __restrict__ out) {
    const int g = blockIdx.x * 256 + threadIdx.x;
    #pragma unroll
    for (int k = 0; k < 4; ++k) {
        const int i = g + k * 262144;
        const int bb = i >> 15;
        const int off = i & 32767;
        *(float4*)(out + ((size_t)bb * (NLC + NLT) + NLC) * ND + (size_t)off * 4) =
            make_float4(0.f, 0.f, 0.f, 0.f);
    }
}

__global__ __launch_bounds__(256) void reduce_g2t(const float* __restrict__ part,
                                                  float* __restrict__ out) {
    const int g = blockIdx.x * 256 + threadIdx.x;
    #pragma unroll
    for (int k = 0; k < 4; ++k) {
        const int i = g + k * 262144;
        const int b = i >> 15;
        const int rem = i & 32767;
        const int row = rem >> 6;
        const int d4 = (rem & 63) * 4;
        const int mb = row >> 7, r = row & 127;
        const size_t base = ((size_t)(b * 16 + mb * 4) * 32768) + (size_t)r * 256 + d4;
        float4 s0 = *(const float4*)(part + base);
        float4 s1 = *(const float4*)(part + base + 32768);
        float4 s2 = *(const float4*)(part + base + 65536);
        float4 s3 = *(const float4*)(part + base + 98304);
        *(float4*)(out + ((size_t)b * (NLC + NLT) + NLC + row) * ND + d4) =
            make_float4(s0.x + s1.x + s2.x + s3.x, s0.y + s1.y + s2.y + s3.y,
                        s0.z + s1.z + s2.z + s3.z, s0.w + s1.w + s2.w + s3.w);
    }
}

__global__ __launch_bounds__(256, 2) void fused_dist_attn(
    const float* __restrict__ ctx, const float* __restrict__ tgt,
    float* __restrict__ out, float* __restrict__ part)
{
    __shared__ __align__(16) unsigned short Klds[2][32 * 256];
    __shared__ __align__(16) unsigned short VTlds[2][256 * 32];
    __shared__ __align__(16) unsigned short Wlds[4 * 32 * 32];
    __shared__ unsigned int KextLds[2][32];

    const int phys = blockIdx.x;
    const int L = (phys & 7) * 128 + (phys >> 3);
    const int isB = (L & 1) == 0;
    const int idx = L >> 1;
    const int b = idx >> 4;
    const float *Q, *KV;
    size_t outbase;
    if (isB) {
        const int mb = (idx >> 2) & 3, nc = idx & 3;
        Q = tgt + ((size_t)b * NLT + mb * 128) * ND;
        KV = ctx + ((size_t)b * NLC + nc * NCHUNK) * ND;
        outbase = ((size_t)b * (NLC + NLT) + NLC + mb * 128) * ND;
    } else {
        const int mb = idx & 15;
        Q = ctx + ((size_t)b * NLC + mb * 128) * ND;
        KV = tgt + (size_t)b * NLT * ND;
        outbase = ((size_t)b * (NLC + NLT) + mb * 128) * ND;
    }

    const int tid = threadIdx.x, wave = tid >> 6, lane = tid & 63;
    const int lr = lane & 15, lq = lane >> 4;

    s16x8 qf[2][8];
    s16x8 qe[2];
    #pragma unroll
    for (int mf = 0; mf < 2; ++mf) {
        const float* qrow = Q + (size_t)(wave * 32 + mf * 16 + lr) * ND;
        float q2 = 0.0f;
        #pragma unroll
        for (int kk = 0; kk < 8; ++kk) {
            const float4 a = *(const float4*)(qrow + kk * 32 + lq * 8);
            const float4 c = *(const float4*)(qrow + kk * 32 + lq * 8 + 4);
            q2 += a.x*a.x + a.y*a.y + a.z*a.z + a.w*a.w;
            q2 += c.x*c.x + c.y*c.y + c.z*c.z + c.w*c.w;
            qf[mf][kk] = cvt8(a, c, -2.0f);
        }
        q2 += __shfl_xor(q2, 16);
        q2 += __shfl_xor(q2, 32);
        union { unsigned int u[4]; s16x8 v; } qu;
        qu.u[0] = (lq == 0) ? (0x3F80u | ((unsigned int)f2bf(q2) << 16)) : 0u;
        qu.u[1] = 0u; qu.u[2] = 0u; qu.u[3] = 0u;
        qe[mf] = qu.v;
    }

    f32x4 acc[2][16];
    #pragma unroll
    for (int mf = 0; mf < 2; ++mf)
        #pragma unroll
        for (int dt = 0; dt < 16; ++dt)
            acc[mf][dt] = (f32x4)(0.0f);

    const int r4 = 8 * wave + 4 * (lane & 1);
    const int d8 = (lane >> 1) * 8;
    float4 ldr[4][2];

    auto LOADT = [&](int n0) {
        #pragma unroll
        for (int rr = 0; rr < 4; ++rr)
            #pragma unroll
            for (int h = 0; h < 2; ++h)
                ldr[rr][h] = *(const float4*)(KV + (size_t)(n0 + r4 + rr) * ND + d8 + 4 * h);
    };

    auto WRITET = [&](int sel) {
        float ps[4];
        unsigned short kb[4][8];
        #pragma unroll
        for (int rr = 0; rr < 4; ++rr) {
            const float4 a = ldr[rr][0], c = ldr[rr][1];
            ps[rr] = a.x*a.x + a.y*a.y + a.z*a.z + a.w*a.w
                   + c.x*c.x + c.y*c.y + c.z*c.z + c.w*c.w;
            kb[rr][0]=f2bf(a.x); kb[rr][1]=f2bf(a.y); kb[rr][2]=f2bf(a.z); kb[rr][3]=f2bf(a.w);
            kb[rr][4]=f2bf(c.x); kb[rr][5]=f2bf(c.y); kb[rr][6]=f2bf(c.z); kb[rr][7]=f2bf(c.w);
            const int r = r4 + rr;
            *(s16x8*)&Klds[sel][r * 256 + (d8 ^ ((r & 7) << 3))] = *(const s16x8*)kb[rr];
        }
        #pragma unroll
        for (int dd = 0; dd < 8; ++dd) {
            const int d = d8 + dd;
            *(ushort4*)&VTlds[sel][d * 32 + (r4 ^ (((d >> 3) & 3) << 3))] =
                make_ushort4(kb[0][dd], kb[1][dd], kb[2][dd], kb[3][dd]);
        }
        #pragma unroll
        for (int rr = 0; rr < 4; ++rr) {
            ps[rr] += __shfl_xor(ps[rr], 2);
            ps[rr] += __shfl_xor(ps[rr], 4);
            ps[rr] += __shfl_xor(ps[rr], 8);
            ps[rr] += __shfl_xor(ps[rr], 16);
            ps[rr] += __shfl_xor(ps[rr], 32);
        }
        if (lane < 2) {
            #pragma unroll
            for (int rr = 0; rr < 4; ++rr)
                KextLds[sel][8 * wave + 4 * lane + rr] =
                    (unsigned int)f2bf(ps[rr]) | 0x3F800000u;
        }
    };

    LOADT(0);
    WRITET(0);

    #pragma unroll 2
    for (int t = 0; t < NITER; ++t) {
        __syncthreads();
        const int sel = t & 1;
        if (t + 1 < NITER) LOADT((t + 1) * 32);

        unsigned int p0 = 0u, p1 = 0u;
        if (lq == 0) { p0 = KextLds[sel][lr]; p1 = KextLds[sel][16 + lr]; }
        union { unsigned int u[4]; s16x8 v; } keu0, keu1;
        keu0.u[0] = p0; keu0.u[1] = 0; keu0.u[2] = 0; keu0.u[3] = 0;
        keu1.u[0] = p1; keu1.u[1] = 0; keu1.u[2] = 0; keu1.u[3] = 0;

        f32x4 sacc[2][2];
        sacc[0][0] = (f32x4)(0.0f); sacc[0][1] = (f32x4)(0.0f);
        sacc[1][0] = (f32x4)(0.0f); sacc[1][1] = (f32x4)(0.0f);
        __builtin_amdgcn_s_setprio(1);
        #pragma unroll
        for (int kk = 0; kk < 8; ++kk) {
            const int cs = (kk * 32 + lq * 8) ^ ((lr & 7) << 3);
            const s16x8 kf0 = *(const s16x8*)&Klds[sel][lr * 256 + cs];
            const s16x8 kf1 = *(const s16x8*)&Klds[sel][(16 + lr) * 256 + cs];
            sacc[0][0] = __builtin_amdgcn_mfma_f32_16x16x32_bf16(kf0, qf[0][kk], sacc[0][0], 0, 0, 0);
            sacc[0][1] = __builtin_amdgcn_mfma_f32_16x16x32_bf16(kf0, qf[1][kk], sacc[0][1], 0, 0, 0);
            sacc[1][0] = __builtin_amdgcn_mfma_f32_16x16x32_bf16(kf1, qf[0][kk], sacc[1][0], 0, 0, 0);
            sacc[1][1] = __builtin_amdgcn_mfma_f32_16x16x32_bf16(kf1, qf[1][kk], sacc[1][1], 0, 0, 0);
        }
        sacc[0][0] = __builtin_amdgcn_mfma_f32_16x16x32_bf16(keu0.v, qe[0], sacc[0][0], 0, 0, 0);
        sacc[0][1] = __builtin_amdgcn_mfma_f32_16x16x32_bf16(keu0.v, qe[1], sacc[0][1], 0, 0, 0);
        sacc[1][0] = __builtin_amdgcn_mfma_f32_16x16x32_bf16(keu1.v, qe[0], sacc[1][0], 0, 0, 0);
        sacc[1][1] = __builtin_amdgcn_mfma_f32_16x16x32_bf16(keu1.v, qe[1], sacc[1][1], 0, 0, 0);
        __builtin_amdgcn_s_setprio(0);

        #pragma unroll
        for (int ns = 0; ns < 2; ++ns) {
            #pragma unroll
            for (int mf = 0; mf < 2; ++mf) {
                unsigned short w4[4];
                #pragma unroll
                for (int j = 0; j < 4; ++j) {
                    float d2 = sacc[ns][mf][j];
                    d2 = d2 > 0.0f ? d2 : 0.0f;
                    w4[j] = f2bf(__builtin_amdgcn_rcpf(1.0f + __builtin_amdgcn_sqrtf(d2)));
                }
                const int row = mf * 16 + lr;
                const int col = (ns * 16 + lq * 4) ^ ((row & 3) << 3);
                *(ushort4*)&Wlds[wave * 1024 + row * 32 + col] =
                    make_ushort4(w4[0], w4[1], w4[2], w4[3]);
            }
        }

        s16x8 wfr[2];
        #pragma unroll
        for (int mf = 0; mf < 2; ++mf)
            wfr[mf] = *(const s16x8*)&Wlds[wave * 1024 + (mf * 16 + lr) * 32 +
                                           ((lq * 8) ^ ((lr & 3) << 3))];
        __builtin_amdgcn_s_setprio(1);
        #pragma unroll
        for (int dt = 0; dt < 16; ++dt) {
            const int vr = dt * 16 + lr;
            const s16x8 vf = *(const s16x8*)&VTlds[sel][vr * 32 +
                                                        ((lq * 8) ^ (((vr >> 3) & 3) << 3))];
            acc[0][dt] = __builtin_amdgcn_mfma_f32_16x16x32_bf16(vf, wfr[0], acc[0][dt], 0, 0, 0);
            acc[1][dt] = __builtin_amdgcn_mfma_f32_16x16x32_bf16(vf, wfr[1], acc[1][dt], 0, 0, 0);
        }
        __builtin_amdgcn_s_setprio(0);

        if (t + 1 < NITER) WRITET(sel ^ 1);
    }

    if (isB) {
        if (part) {
            float* p = part + (size_t)idx * 32768;
            #pragma unroll
            for (int mf = 0; mf < 2; ++mf) {
                const size_t rowbase = (size_t)(wave * 32 + mf * 16 + lr) * ND;
                #pragma unroll
                for (int dt = 0; dt < 16; ++dt) {
                    const f32x4 v = acc[mf][dt];
                    *(float4*)(p + rowbase + dt * 16 + lq * 4) = make_float4(v[0], v[1], v[2], v[3]);
                }
            }
        } else {
            #pragma unroll
            for (int mf = 0; mf < 2; ++mf) {
                float* rowp = out + outbase + (size_t)(wave * 32 + mf * 16 + lr) * ND;
                #pragma unroll
                for (int dt = 0; dt < 16; ++dt)
                    #pragma unroll
                    for (int j = 0; j < 4; ++j)
                        atomicAdd(rowp + dt * 16 + lq * 4 + j, acc[mf][dt][j]);
            }
        }
    } else {
        #pragma unroll
        for (int mf = 0; mf < 2; ++mf) {
            const size_t rowbase = outbase + (size_t)(wave * 32 + mf * 16 + lr) * ND;
            #pragma unroll
            for (int dt = 0; dt < 16; ++dt) {
                const f32x4 v = acc[mf][dt];
                *(float4*)(out + rowbase + dt * 16 + lq * 4) = make_float4(v[0], v[1], v[2], v[3]);
            }
        }
    }
}

extern "C" void kernel_launch(void* const* d_in, const int* in_sizes, int n_in,
                              void* d_out, int out_size, void* d_ws, size_t ws_size,
                              hipStream_t stream) {
    const float* ctx = (const float*)d_in[0];   // [32, 2048, 256] fp32
    const float* tgt = (const float*)d_in[1];   // [32, 512, 256] fp32
    float* out = (float*)d_out;                 // [32, 2560, 256] fp32

    const size_t OFF_NORMS = 0;
    const size_t OFF_CTXB  = 327680;                         // norms: 81920*4
    const size_t OFF_TGTB  = OFF_CTXB + 33554432;            // ctx_bf
    const size_t OFF_W     = OFF_TGTB + 8388608;             // tgt_bf
    const size_t OFF_WT    = OFF_W + 67108864;
    const size_t OFF_PART  = OFF_WT + 67108864;
    const size_t NEED_B    = OFF_PART;                       // 176,488,448
    const size_t NEED_FULL = OFF_PART + 67108864;            // 243,597,312

    char* ws = (char*)d_ws;
    if (ws_size >= NEED_B) {
        float* norms = (float*)(ws + OFF_NORMS);
        unsigned short* ctxb = (unsigned short*)(ws + OFF_CTXB);
        unsigned short* tgtb = (unsigned short*)(ws + OFF_TGTB);
        unsigned short* Wg   = (unsigned short*)(ws + OFF_W);
        unsigned short* WTg  = (unsigned short*)(ws + OFF_WT);

        prep_kernel<<<20480, 256, 0, stream>>>(ctx, tgt, norms, ctxb, tgtb);
        k1_weights<<<2048, 256, 0, stream>>>(ctxb, tgtb, norms, Wg, WTg);
        k23_gemm<<<512, 512, 0, stream>>>(tgtb, Wg, out, nullptr, 2);
        if (ws_size >= NEED_FULL) {
            float* part = (float*)(ws + OFF_PART);
            k23_gemm<<<512, 512, 0, stream>>>(ctxb, WTg, out, part, 3);
            reduce_part<<<1024, 256, 0, stream>>>(part, out);
        } else {
            k23_gemm<<<128, 512, 0, stream>>>(ctxb, WTg, out, nullptr, 4);
        }
    } else {
        const size_t need = (size_t)512 * 128 * 256 * 4;
        if (ws_size >= need) {
            float* part = (float*)d_ws;
            fused_dist_attn<<<1024, 256, 0, stream>>>(ctx, tgt, out, part);
            reduce_g2t<<<1024, 256, 0, stream>>>(part, out);
        } else {
            zero_g2t<<<1024, 256, 0, stream>>>(out);
            fused_dist_attn<<<1024, 256, 0, stream>>>(ctx, tgt, out, nullptr);
        }
    }
}

// Round 7
// 188.871 us; speedup vs baseline: 2.7209x; 1.3161x over previous
//
#include <hip/hip_runtime.h>

typedef float f32x4 __attribute__((ext_vector_type(4)));
typedef short s16x8 __attribute__((ext_vector_type(8)));

#define NB_    32
#define NLC    2048
#define NLT    512
#define ND     256
#define NCHUNK 512
#define NITER  (NCHUNK / 32)

__device__ __forceinline__ unsigned short f2bf(float f) {
    union { float f; unsigned int u; } v; v.f = f;
    unsigned int r = v.u + 0x7FFFu + ((v.u >> 16) & 1u);   // RNE to bf16
    return (unsigned short)(r >> 16);
}

__device__ __forceinline__ s16x8 cvt8(float4 a, float4 c, float s) {
    s16x8 f;
    f[0]=(short)f2bf(s*a.x); f[1]=(short)f2bf(s*a.y); f[2]=(short)f2bf(s*a.z); f[3]=(short)f2bf(s*a.w);
    f[4]=(short)f2bf(s*c.x); f[5]=(short)f2bf(s*c.y); f[6]=(short)f2bf(s*c.z); f[7]=(short)f2bf(s*c.w);
    return f;
}

// async global->LDS, 16B per lane (dest = wave-uniform base + lane*16)
__device__ __forceinline__ void glds16(const void* g, void* l) {
    __builtin_amdgcn_global_load_lds(
        (const __attribute__((address_space(1))) unsigned int*)g,
        (__attribute__((address_space(3))) unsigned int*)l, 16, 0, 0);
}

// ---------------------------------------------------------------------------
// Prep: bf16 copies of ctx/tgt + row squared-norms. One wave per row.
// ---------------------------------------------------------------------------
__global__ __launch_bounds__(256) void prep_kernel(
    const float* __restrict__ ctx, const float* __restrict__ tgt,
    float* __restrict__ norms,
    unsigned short* __restrict__ ctxb, unsigned short* __restrict__ tgtb)
{
    const int wave = threadIdx.x >> 6;
    const int lane = threadIdx.x & 63;
    const int rid = blockIdx.x * 4 + wave;
    const float* row;
    unsigned short* drow;
    if (rid < NB_ * NLC) { row = ctx + (size_t)rid * ND; drow = ctxb + (size_t)rid * ND; }
    else { row = tgt + (size_t)(rid - NB_ * NLC) * ND; drow = tgtb + (size_t)(rid - NB_ * NLC) * ND; }
    const float4 v = *(const float4*)(row + lane * 4);
    *(ushort4*)(drow + lane * 4) = make_ushort4(f2bf(v.x), f2bf(v.y), f2bf(v.z), f2bf(v.w));
    float s = v.x * v.x + v.y * v.y + v.z * v.z + v.w * v.w;
    #pragma unroll
    for (int off = 32; off >= 1; off >>= 1) s += __shfl_xor(s, off);
    if (lane == 0) norms[rid] = s;
}

// ---------------------------------------------------------------------------
// Transpose bf16 copies: per batch, [L][256] -> [256][L]. 64x64 tiles via LDS.
// grid: 4096 ctx tiles + 1024 tgt tiles.
// ---------------------------------------------------------------------------
__global__ __launch_bounds__(256) void transpose_bf(
    const unsigned short* __restrict__ ctxb, const unsigned short* __restrict__ tgtb,
    unsigned short* __restrict__ ctxT, unsigned short* __restrict__ tgtT)
{
    __shared__ unsigned short tile[64][72];
    const int id = blockIdx.x;
    const unsigned short* in;
    unsigned short* outp;
    int ldL;
    if (id < 4096) {
        const int b = id >> 7, r = id & 127, lt = r >> 2, dt = r & 3;
        in   = ctxb + ((size_t)b * NLC + lt * 64) * ND + dt * 64;
        outp = ctxT + ((size_t)b * ND + dt * 64) * NLC + lt * 64;
        ldL = NLC;
    } else {
        const int id2 = id - 4096;
        const int b = id2 >> 5, r = id2 & 31, lt = r >> 2, dt = r & 3;
        in   = tgtb + ((size_t)b * NLT + lt * 64) * ND + dt * 64;
        outp = tgtT + ((size_t)b * ND + dt * 64) * NLT + lt * 64;
        ldL = NLT;
    }
    const int t = threadIdx.x;
    const int r0 = t >> 2, c0 = t & 3;
    const s16x8 v0 = *(const s16x8*)&in[(size_t)r0 * ND + c0 * 8];
    const s16x8 v1 = *(const s16x8*)&in[(size_t)r0 * ND + (c0 + 4) * 8];
    *(s16x8*)&tile[r0][c0 * 8] = v0;
    *(s16x8*)&tile[r0][(c0 + 4) * 8] = v1;
    __syncthreads();
    unsigned short buf[16];
    #pragma unroll
    for (int i = 0; i < 16; ++i) buf[i] = tile[(t & 3) * 16 + i][t >> 2];
    unsigned short* op = outp + (size_t)(t >> 2) * ldL + (t & 3) * 16;
    *(s16x8*)&op[0] = *(const s16x8*)&buf[0];
    *(s16x8*)&op[8] = *(const s16x8*)&buf[8];
}

// ---------------------------------------------------------------------------
// K1 (m97-structure): S = ctx.tgt^T per batch via LDS-staged bf16 GEMM.
// Epilogue: w = rcp(1+sqrt(max(c2+t2-2S,0))) -> relay -> W[c][t], WT[t][c].
// ---------------------------------------------------------------------------
__global__ __launch_bounds__(256, 2) void k1_weights(
    const unsigned short* __restrict__ ctxb, const unsigned short* __restrict__ tgtb,
    const float* __restrict__ norms,
    unsigned short* __restrict__ Wg, unsigned short* __restrict__ WTg)
{
    __shared__ __align__(16) unsigned short Alds[2][128 * 64];   // [c][k] swz
    __shared__ __align__(16) unsigned short Blds[2][128 * 64];   // [t][k] swz
    __shared__ __align__(16) unsigned short relay[4][16 * 128];

    const int phys = blockIdx.x;
    const int L = (phys & 7) * 256 + (phys >> 3);   // grid 2048, bijective
    const int b = L >> 6;
    const int r = L & 63;
    const int cb = r >> 2, tb = r & 3;

    const int tid = threadIdx.x, wave = tid >> 6, lane = tid & 63;
    const int lr = lane & 15, lq = lane >> 4;
    const int cw = cb * 128 + wave * 32;

    const unsigned short* Actx = ctxb + ((size_t)b * NLC + cb * 128) * ND;
    const unsigned short* Btgt = tgtb + ((size_t)b * NLT + tb * 128) * ND;

    auto STAGE = [&](int buf, int ks) {
        #pragma unroll
        for (int i = 0; i < 4; ++i) {
            const int q = wave * 4 + i;
            const int rloc = q * 8 + (lane >> 3);
            const int gcol = (lane & 7) ^ (rloc & 7);
            glds16(Actx + (size_t)rloc * ND + ks * 64 + gcol * 8, &Alds[buf][q * 512]);
            glds16(Btgt + (size_t)rloc * ND + ks * 64 + gcol * 8, &Blds[buf][q * 512]);
        }
    };

    f32x4 acc[2][8];
    #pragma unroll
    for (int mf = 0; mf < 2; ++mf)
        #pragma unroll
        for (int nf = 0; nf < 8; ++nf) acc[mf][nf] = (f32x4)(0.0f);

    STAGE(0, 0);
    int buf = 0;
    for (int ks = 0; ks < 4; ++ks) {
        __syncthreads();
        if (ks < 3) STAGE(buf ^ 1, ks + 1);
        #pragma unroll
        for (int kk = 0; kk < 2; ++kk) {
            s16x8 af[2];
            #pragma unroll
            for (int mf = 0; mf < 2; ++mf) {
                const int row = wave * 32 + mf * 16 + lr;
                af[mf] = *(const s16x8*)&Alds[buf][row * 64 + (((kk * 4 + lq) ^ (row & 7)) * 8)];
            }
            #pragma unroll
            for (int nf = 0; nf < 8; ++nf) {
                const int row = nf * 16 + lr;
                const s16x8 bf = *(const s16x8*)&Blds[buf][row * 64 + (((kk * 4 + lq) ^ (row & 7)) * 8)];
                acc[0][nf] = __builtin_amdgcn_mfma_f32_16x16x32_bf16(af[0], bf, acc[0][nf], 0, 0, 0);
                acc[1][nf] = __builtin_amdgcn_mfma_f32_16x16x32_bf16(af[1], bf, acc[1][nf], 0, 0, 0);
            }
        }
        buf ^= 1;
    }

    float c2[2][4], t2[8];
    #pragma unroll
    for (int mf = 0; mf < 2; ++mf)
        #pragma unroll
        for (int j = 0; j < 4; ++j)
            c2[mf][j] = norms[b * NLC + cw + mf * 16 + lq * 4 + j];
    #pragma unroll
    for (int nf = 0; nf < 8; ++nf)
        t2[nf] = norms[NB_ * NLC + b * NLT + tb * 128 + nf * 16 + lr];

    __syncthreads();
    #pragma unroll
    for (int mf = 0; mf < 2; ++mf) {
        #pragma unroll
        for (int nf = 0; nf < 8; ++nf) {
            #pragma unroll
            for (int j = 0; j < 4; ++j) {
                float d2 = c2[mf][j] + t2[nf] - 2.0f * acc[mf][nf][j];
                d2 = d2 > 0.0f ? d2 : 0.0f;
                const float w = __builtin_amdgcn_rcpf(1.0f + __builtin_amdgcn_sqrtf(d2));
                const int row = lq * 4 + j;
                relay[wave][row * 128 + ((nf * 16 + lr) ^ ((row & 7) << 3))] = f2bf(w);
            }
        }
        __syncthreads();
        {
            const int rrow = lane >> 2;
            const int cbs = (lane & 3) * 32;
            const size_t wrow = ((size_t)b * NLC + cw + mf * 16 + rrow) * NLT + tb * 128;
            #pragma unroll
            for (int e = 0; e < 4; ++e) {
                const int colb = cbs + e * 8;
                const s16x8 v = *(const s16x8*)&relay[wave][rrow * 128 + (colb ^ ((rrow & 7) << 3))];
                *(s16x8*)&Wg[wrow + colb] = v;
            }
        }
        #pragma unroll
        for (int c = 0; c < 2; ++c) {
            const int tc = (lane << 1) | c;
            unsigned short colv[16];
            #pragma unroll
            for (int rr = 0; rr < 16; ++rr)
                colv[rr] = relay[wave][rr * 128 + (tc ^ ((rr & 7) << 3))];
            const size_t wtrow = ((size_t)b * NLT + tb * 128 + tc) * NLC + cw + mf * 16;
            *(s16x8*)&WTg[wtrow]     = *(const s16x8*)&colv[0];
            *(s16x8*)&WTg[wtrow + 8] = *(const s16x8*)&colv[8];
        }
        __syncthreads();
    }
}

// ---------------------------------------------------------------------------
// K23 v2: O^T GEMM, tile 128 cols x 256 d (full D), BK=64, K=512 per block.
//   A (srcT = tgtT/ctxT rows [d][k]) staged via global_load_lds, pre-swizzled.
//   B (W/WT rows [col][k]) read as direct global fragments (each byte once).
//   mode 2: g2c direct store; mode 3: g2t k-chunk partials.
// mfma(af=srcT-frag, bf=W-frag) -> C row=d (float4 stores), col=W-row.
// ---------------------------------------------------------------------------
__global__ __launch_bounds__(256, 2) void k23v2(
    const unsigned short* __restrict__ At, const unsigned short* __restrict__ Bw,
    float* __restrict__ outp, int mode)
{
    __shared__ __align__(16) unsigned short Slds[2][256 * 64];   // [d][k] swz

    const int phys = blockIdx.x;
    const int L = (phys & 7) * 64 + (phys >> 3);   // grid 512, bijective
    int ldk;
    const unsigned short *Ab, *Bb;
    float* outB;
    if (mode == 2) {
        const int b = L >> 4, cb = L & 15;
        ldk = NLT;
        Ab = At + (size_t)b * ND * NLT;
        Bb = Bw + ((size_t)b * NLC + cb * 128) * NLT;
        outB = outp + ((size_t)b * (NLC + NLT) + cb * 128) * ND;
    } else {
        const int b = L >> 4, j = L & 15, cb = j & 3, ch = j >> 2;
        ldk = NLC;
        Ab = At + (size_t)b * ND * NLC + ch * 512;
        Bb = Bw + ((size_t)b * NLT + cb * 128) * NLC + ch * 512;
        outB = outp + ((size_t)(ch * NB_ + b) * NLT + cb * 128) * ND;   // part
    }

    const int tid = threadIdx.x, wave = tid >> 6, lane = tid & 63;
    const int lr = lane & 15, lq = lane >> 4;

    const int srow = tid >> 3;       // wave*8 + (lane>>3)
    const int schunk = tid & 7;

    auto STAGE = [&](int buf, int ks) {
        #pragma unroll
        for (int i = 0; i < 8; ++i) {
            const int row = i * 32 + srow;
            const int gcol = schunk ^ (row & 7);
            glds16(Ab + (size_t)row * ldk + ks * 64 + gcol * 8,
                   &Slds[buf][(i * 32 + wave * 8) * 64]);
        }
    };

    f32x4 acc[16][2];
    #pragma unroll
    for (int mf = 0; mf < 16; ++mf) { acc[mf][0] = (f32x4)(0.0f); acc[mf][1] = (f32x4)(0.0f); }

    STAGE(0, 0);
    for (int ks = 0; ks < 8; ++ks) {
        __syncthreads();               // drains vmcnt -> buf ready
        const int buf = ks & 1;
        if (ks < 7) STAGE(buf ^ 1, ks + 1);

        // B fragments direct from global (rows = cols owned by this wave)
        s16x8 bfr[2][2];
        #pragma unroll
        for (int j = 0; j < 2; ++j)
            #pragma unroll
            for (int kk = 0; kk < 2; ++kk)
                bfr[j][kk] = *(const s16x8*)&Bb[(size_t)(wave * 32 + j * 16 + lr) * ldk +
                                                ks * 64 + kk * 32 + lq * 8];

        __builtin_amdgcn_s_setprio(1);
        #pragma unroll
        for (int kk = 0; kk < 2; ++kk) {
            #pragma unroll
            for (int mf = 0; mf < 16; ++mf) {
                const int row = mf * 16 + lr;
                const s16x8 af = *(const s16x8*)&Slds[buf][row * 64 +
                                                           (((kk * 4 + lq) ^ (row & 7)) * 8)];
                acc[mf][0] = __builtin_amdgcn_mfma_f32_16x16x32_bf16(af, bfr[0][kk], acc[mf][0], 0, 0, 0);
                acc[mf][1] = __builtin_amdgcn_mfma_f32_16x16x32_bf16(af, bfr[1][kk], acc[mf][1], 0, 0, 0);
            }
        }
        __builtin_amdgcn_s_setprio(0);
    }

    // epilogue: C/D row = d = mf*16 + lq*4 + j (contiguous float4), col from lr
    #pragma unroll
    for (int j = 0; j < 2; ++j) {
        const int col = wave * 32 + j * 16 + lr;
        float* rp = outB + (size_t)col * ND;
        #pragma unroll
        for (int mf = 0; mf < 16; ++mf) {
            const f32x4 v = acc[mf][j];
            *(float4*)(rp + mf * 16 + lq * 4) = make_float4(v[0], v[1], v[2], v[3]);
        }
    }
}

// ---------------------------------------------------------------------------
// Reduce 4 k-chunk partials into g2t region of out.
// ---------------------------------------------------------------------------
__global__ __launch_bounds__(256) void reduce_part(const float* __restrict__ part,
                                                   float* __restrict__ out) {
    const int g = blockIdx.x * 256 + threadIdx.x;
    #pragma unroll
    for (int k = 0; k < 4; ++k) {
        const int i = g + k * 262144;           // float4 idx over [32][512][64]
        const int b = i >> 15;
        const int rem = i & 32767;
        const int t = rem >> 6;
        const int d4 = (rem & 63) * 4;
        const size_t base = ((size_t)b * NLT + t) * ND + d4;
        const float4 s0 = *(const float4*)(part + base);
        const float4 s1 = *(const float4*)(part + base + 4194304);
        const float4 s2 = *(const float4*)(part + base + 8388608);
        const float4 s3 = *(const float4*)(part + base + 12582912);
        *(float4*)(out + ((size_t)b * (NLC + NLT) + NLC + t) * ND + d4) =
            make_float4(s0.x + s1.x + s2.x + s3.x, s0.y + s1.y + s2.y + s3.y,
                        s0.z + s1.z + s2.z + s3.z, s0.w + s1.w + s2.w + s3.w);
    }
}

// ===========================================================================
// R4 fused fallback (proven-correct) for small workspaces.
// ===========================================================================
__global__ __launch_bounds__(256) void zero_g2t(float* __restrict__ out) {
    const int g = blockIdx.x * 256 + threadIdx.x;
    #pragma unroll
    for (int k = 0; k < 4; ++k) {
        const int i = g + k * 262144;
        const int bb = i >> 15;
        const int off = i & 32767;
        *(float4*)(out + ((size_t)bb * (NLC + NLT) + NLC) * ND + (size_t)off * 4) =
            make_float4(0.f, 0.f, 0.f, 0.f);
    }
}

__global__ __launch_bounds__(256) void reduce_g2t(const float* __restrict__ part,
                                                  float* __restrict__ out) {
    const int g = blockIdx.x * 256 + threadIdx.x;
    #pragma unroll
    for (int k = 0; k < 4; ++k) {
        const int i = g + k * 262144;
        const int b = i >> 15;
        const int rem = i & 32767;
        const int row = rem >> 6;
        const int d4 = (rem & 63) * 4;
        const int mb = row >> 7, r = row & 127;
        const size_t base = ((size_t)(b * 16 + mb * 4) * 32768) + (size_t)r * 256 + d4;
        float4 s0 = *(const float4*)(part + base);
        float4 s1 = *(const float4*)(part + base + 32768);
        float4 s2 = *(const float4*)(part + base + 65536);
        float4 s3 = *(const float4*)(part + base + 98304);
        *(float4*)(out + ((size_t)b * (NLC + NLT) + NLC + row) * ND + d4) =
            make_float4(s0.x + s1.x + s2.x + s3.x, s0.y + s1.y + s2.y + s3.y,
                        s0.z + s1.z + s2.z + s3.z, s0.w + s1.w + s2.w + s3.w);
    }
}

__global__ __launch_bounds__(256, 2) void fused_dist_attn(
    const float* __restrict__ ctx, const float* __restrict__ tgt,
    float* __restrict__ out, float* __restrict__ part)
{
    __shared__ __align__(16) unsigned short Klds[2][32 * 256];
    __shared__ __align__(16) unsigned short VTlds[2][256 * 32];
    __shared__ __align__(16) unsigned short Wlds[4 * 32 * 32];
    __shared__ unsigned int KextLds[2][32];

    const int phys = blockIdx.x;
    const int L = (phys & 7) * 128 + (phys >> 3);
    const int isB = (L & 1) == 0;
    const int idx = L >> 1;
    const int b = idx >> 4;
    const float *Q, *KV;
    size_t outbase;
    if (isB) {
        const int mb = (idx >> 2) & 3, nc = idx & 3;
        Q = tgt + ((size_t)b * NLT + mb * 128) * ND;
        KV = ctx + ((size_t)b * NLC + nc * NCHUNK) * ND;
        outbase = ((size_t)b * (NLC + NLT) + NLC + mb * 128) * ND;
    } else {
        const int mb = idx & 15;
        Q = ctx + ((size_t)b * NLC + mb * 128) * ND;
        KV = tgt + (size_t)b * NLT * ND;
        outbase = ((size_t)b * (NLC + NLT) + mb * 128) * ND;
    }

    const int tid = threadIdx.x, wave = tid >> 6, lane = tid & 63;
    const int lr = lane & 15, lq = lane >> 4;

    s16x8 qf[2][8];
    s16x8 qe[2];
    #pragma unroll
    for (int mf = 0; mf < 2; ++mf) {
        const float* qrow = Q + (size_t)(wave * 32 + mf * 16 + lr) * ND;
        float q2 = 0.0f;
        #pragma unroll
        for (int kk = 0; kk < 8; ++kk) {
            const float4 a = *(const float4*)(qrow + kk * 32 + lq * 8);
            const float4 c = *(const float4*)(qrow + kk * 32 + lq * 8 + 4);
            q2 += a.x*a.x + a.y*a.y + a.z*a.z + a.w*a.w;
            q2 += c.x*c.x + c.y*c.y + c.z*c.z + c.w*c.w;
            qf[mf][kk] = cvt8(a, c, -2.0f);
        }
        q2 += __shfl_xor(q2, 16);
        q2 += __shfl_xor(q2, 32);
        union { unsigned int u[4]; s16x8 v; } qu;
        qu.u[0] = (lq == 0) ? (0x3F80u | ((unsigned int)f2bf(q2) << 16)) : 0u;
        qu.u[1] = 0u; qu.u[2] = 0u; qu.u[3] = 0u;
        qe[mf] = qu.v;
    }

    f32x4 acc[2][16];
    #pragma unroll
    for (int mf = 0; mf < 2; ++mf)
        #pragma unroll
        for (int dt = 0; dt < 16; ++dt)
            acc[mf][dt] = (f32x4)(0.0f);

    const int r4 = 8 * wave + 4 * (lane & 1);
    const int d8 = (lane >> 1) * 8;
    float4 ldr[4][2];

    auto LOADT = [&](int n0) {
        #pragma unroll
        for (int rr = 0; rr < 4; ++rr)
            #pragma unroll
            for (int h = 0; h < 2; ++h)
                ldr[rr][h] = *(const float4*)(KV + (size_t)(n0 + r4 + rr) * ND + d8 + 4 * h);
    };

    auto WRITET = [&](int sel) {
        float ps[4];
        unsigned short kb[4][8];
        #pragma unroll
        for (int rr = 0; rr < 4; ++rr) {
            const float4 a = ldr[rr][0], c = ldr[rr][1];
            ps[rr] = a.x*a.x + a.y*a.y + a.z*a.z + a.w*a.w
                   + c.x*c.x + c.y*c.y + c.z*c.z + c.w*c.w;
            kb[rr][0]=f2bf(a.x); kb[rr][1]=f2bf(a.y); kb[rr][2]=f2bf(a.z); kb[rr][3]=f2bf(a.w);
            kb[rr][4]=f2bf(c.x); kb[rr][5]=f2bf(c.y); kb[rr][6]=f2bf(c.z); kb[rr][7]=f2bf(c.w);
            const int r = r4 + rr;
            *(s16x8*)&Klds[sel][r * 256 + (d8 ^ ((r & 7) << 3))] = *(const s16x8*)kb[rr];
        }
        #pragma unroll
        for (int dd = 0; dd < 8; ++dd) {
            const int d = d8 + dd;
            *(ushort4*)&VTlds[sel][d * 32 + (r4 ^ (((d >> 3) & 3) << 3))] =
                make_ushort4(kb[0][dd], kb[1][dd], kb[2][dd], kb[3][dd]);
        }
        #pragma unroll
        for (int rr = 0; rr < 4; ++rr) {
            ps[rr] += __shfl_xor(ps[rr], 2);
            ps[rr] += __shfl_xor(ps[rr], 4);
            ps[rr] += __shfl_xor(ps[rr], 8);
            ps[rr] += __shfl_xor(ps[rr], 16);
            ps[rr] += __shfl_xor(ps[rr], 32);
        }
        if (lane < 2) {
            #pragma unroll
            for (int rr = 0; rr < 4; ++rr)
                KextLds[sel][8 * wave + 4 * lane + rr] =
                    (unsigned int)f2bf(ps[rr]) | 0x3F800000u;
        }
    };

    LOADT(0);
    WRITET(0);

    #pragma unroll 2
    for (int t = 0; t < NITER; ++t) {
        __syncthreads();
        const int sel = t & 1;
        if (t + 1 < NITER) LOADT((t + 1) * 32);

        unsigned int p0 = 0u, p1 = 0u;
        if (lq == 0) { p0 = KextLds[sel][lr]; p1 = KextLds[sel][16 + lr]; }
        union { unsigned int u[4]; s16x8 v; } keu0, keu1;
        keu0.u[0] = p0; keu0.u[1] = 0; keu0.u[2] = 0; keu0.u[3] = 0;
        keu1.u[0] = p1; keu1.u[1] = 0; keu1.u[2] = 0; keu1.u[3] = 0;

        f32x4 sacc[2][2];
        sacc[0][0] = (f32x4)(0.0f); sacc[0][1] = (f32x4)(0.0f);
        sacc[1][0] = (f32x4)(0.0f); sacc[1][1] = (f32x4)(0.0f);
        __builtin_amdgcn_s_setprio(1);
        #pragma unroll
        for (int kk = 0; kk < 8; ++kk) {
            const int cs = (kk * 32 + lq * 8) ^ ((lr & 7) << 3);
            const s16x8 kf0 = *(const s16x8*)&Klds[sel][lr * 256 + cs];
            const s16x8 kf1 = *(const s16x8*)&Klds[sel][(16 + lr) * 256 + cs];
            sacc[0][0] = __builtin_amdgcn_mfma_f32_16x16x32_bf16(kf0, qf[0][kk], sacc[0][0], 0, 0, 0);
            sacc[0][1] = __builtin_amdgcn_mfma_f32_16x16x32_bf16(kf0, qf[1][kk], sacc[0][1], 0, 0, 0);
            sacc[1][0] = __builtin_amdgcn_mfma_f32_16x16x32_bf16(kf1, qf[0][kk], sacc[1][0], 0, 0, 0);
            sacc[1][1] = __builtin_amdgcn_mfma_f32_16x16x32_bf16(kf1, qf[1][kk], sacc[1][1], 0, 0, 0);
        }
        sacc[0][0] = __builtin_amdgcn_mfma_f32_16x16x32_bf16(keu0.v, qe[0], sacc[0][0], 0, 0, 0);
        sacc[0][1] = __builtin_amdgcn_mfma_f32_16x16x32_bf16(keu0.v, qe[1], sacc[0][1], 0, 0, 0);
        sacc[1][0] = __builtin_amdgcn_mfma_f32_16x16x32_bf16(keu1.v, qe[0], sacc[1][0], 0, 0, 0);
        sacc[1][1] = __builtin_amdgcn_mfma_f32_16x16x32_bf16(keu1.v, qe[1], sacc[1][1], 0, 0, 0);
        __builtin_amdgcn_s_setprio(0);

        #pragma unroll
        for (int ns = 0; ns < 2; ++ns) {
            #pragma unroll
            for (int mf = 0; mf < 2; ++mf) {
                unsigned short w4[4];
                #pragma unroll
                for (int j = 0; j < 4; ++j) {
                    float d2 = sacc[ns][mf][j];
                    d2 = d2 > 0.0f ? d2 : 0.0f;
                    w4[j] = f2bf(__builtin_amdgcn_rcpf(1.0f + __builtin_amdgcn_sqrtf(d2)));
                }
                const int row = mf * 16 + lr;
                const int col = (ns * 16 + lq * 4) ^ ((row & 3) << 3);
                *(ushort4*)&Wlds[wave * 1024 + row * 32 + col] =
                    make_ushort4(w4[0], w4[1], w4[2], w4[3]);
            }
        }

        s16x8 wfr[2];
        #pragma unroll
        for (int mf = 0; mf < 2; ++mf)
            wfr[mf] = *(const s16x8*)&Wlds[wave * 1024 + (mf * 16 + lr) * 32 +
                                           ((lq * 8) ^ ((lr & 3) << 3))];
        __builtin_amdgcn_s_setprio(1);
        #pragma unroll
        for (int dt = 0; dt < 16; ++dt) {
            const int vr = dt * 16 + lr;
            const s16x8 vf = *(const s16x8*)&VTlds[sel][vr * 32 +
                                                        ((lq * 8) ^ (((vr >> 3) & 3) << 3))];
            acc[0][dt] = __builtin_amdgcn_mfma_f32_16x16x32_bf16(vf, wfr[0], acc[0][dt], 0, 0, 0);
            acc[1][dt] = __builtin_amdgcn_mfma_f32_16x16x32_bf16(vf, wfr[1], acc[1][dt], 0, 0, 0);
        }
        __builtin_amdgcn_s_setprio(0);

        if (t + 1 < NITER) WRITET(sel ^ 1);
    }

    if (isB) {
        if (part) {
            float* p = part + (size_t)idx * 32768;
            #pragma unroll
            for (int mf = 0; mf < 2; ++mf) {
                const size_t rowbase = (size_t)(wave * 32 + mf * 16 + lr) * ND;
                #pragma unroll
                for (int dt = 0; dt < 16; ++dt) {
                    const f32x4 v = acc[mf][dt];
                    *(float4*)(p + rowbase + dt * 16 + lq * 4) = make_float4(v[0], v[1], v[2], v[3]);
                }
            }
        } else {
            #pragma unroll
            for (int mf = 0; mf < 2; ++mf) {
                float* rowp = out + outbase + (size_t)(wave * 32 + mf * 16 + lr) * ND;
                #pragma unroll
                for (int dt = 0; dt < 16; ++dt)
                    #pragma unroll
                    for (int j = 0; j < 4; ++j)
                        atomicAdd(rowp + dt * 16 + lq * 4 + j, acc[mf][dt][j]);
            }
        }
    } else {
        #pragma unroll
        for (int mf = 0; mf < 2; ++mf) {
            const size_t rowbase = outbase + (size_t)(wave * 32 + mf * 16 + lr) * ND;
            #pragma unroll
            for (int dt = 0; dt < 16; ++dt) {
                const f32x4 v = acc[mf][dt];
                *(float4*)(out + rowbase + dt * 16 + lq * 4) = make_float4(v[0], v[1], v[2], v[3]);
            }
        }
    }
}

extern "C" void kernel_launch(void* const* d_in, const int* in_sizes, int n_in,
                              void* d_out, int out_size, void* d_ws, size_t ws_size,
                              hipStream_t stream) {
    const float* ctx = (const float*)d_in[0];   // [32, 2048, 256] fp32
    const float* tgt = (const float*)d_in[1];   // [32, 512, 256] fp32
    float* out = (float*)d_out;                 // [32, 2560, 256] fp32

    const size_t OFF_NORMS = 0;
    const size_t OFF_CTXB  = 327680;
    const size_t OFF_TGTB  = OFF_CTXB + 33554432;
    const size_t OFF_CTXT  = OFF_TGTB + 8388608;
    const size_t OFF_TGTT  = OFF_CTXT + 33554432;
    const size_t OFF_W     = OFF_TGTT + 8388608;
    const size_t OFF_WT    = OFF_W + 67108864;
    const size_t NEED_NEW  = OFF_WT + 67108864;   // 218,431,488

    char* ws = (char*)d_ws;
    if (ws_size >= NEED_NEW) {
        float* norms = (float*)(ws + OFF_NORMS);
        unsigned short* ctxb = (unsigned short*)(ws + OFF_CTXB);
        unsigned short* tgtb = (unsigned short*)(ws + OFF_TGTB);
        unsigned short* ctxT = (unsigned short*)(ws + OFF_CTXT);
        unsigned short* tgtT = (unsigned short*)(ws + OFF_TGTT);
        unsigned short* Wg   = (unsigned short*)(ws + OFF_W);
        unsigned short* WTg  = (unsigned short*)(ws + OFF_WT);
        float* part = (float*)(ws + OFF_W);       // aliases W (dead after mode2)

        prep_kernel<<<20480, 256, 0, stream>>>(ctx, tgt, norms, ctxb, tgtb);
        transpose_bf<<<5120, 256, 0, stream>>>(ctxb, tgtb, ctxT, tgtT);
        k1_weights<<<2048, 256, 0, stream>>>(ctxb, tgtb, norms, Wg, WTg);
        k23v2<<<512, 256, 0, stream>>>(tgtT, Wg, out, 2);
        k23v2<<<512, 256, 0, stream>>>(ctxT, WTg, part, 3);
        reduce_part<<<1024, 256, 0, stream>>>(part, out);
    } else {
        const size_t need = (size_t)512 * 128 * 256 * 4;
        if (ws_size >= need) {
            float* part = (float*)d_ws;
            fused_dist_attn<<<1024, 256, 0, stream>>>(ctx, tgt, out, part);
            reduce_g2t<<<1024, 256, 0, stream>>>(part, out);
        } else {
            zero_g2t<<<1024, 256, 0, stream>>>(out);
            fused_dist_attn<<<1024, 256, 0, stream>>>(ctx, tgt, out, nullptr);
        }
    }
}